// Round 12
// baseline (1751.063 us; speedup 1.0000x reference)
//
#include <hip/hip_runtime.h>

typedef __attribute__((ext_vector_type(8))) _Float16 half8;
typedef __attribute__((ext_vector_type(4))) _Float16 half4;
typedef __attribute__((ext_vector_type(4))) float f32x4;

#define N_NODES 6272
#define CDIM    2048
#define ODIM    512
#define NT      25       // 256-node panels (ceil 6272/256)
#define NSLOT   200      // 25 panels * 8 candidates per node
#define GRID_G  328      // 8 x 41 (325 live triangle tiles + 3 dead)

// ---------------- workspace layout (bytes) ----------------
#define XHI_OFF    0ul
#define XLO_OFF    25690112ul
#define CANDV_OFF  51380224ul          // 6272*200*4 = 5,017,600
#define CANDI_OFF  56397824ul          // 6272*200*2 = 2,508,800 (u16)
#define SQ_OFF     58906624ul
#define KNN_OFF    58931712ul
#define DEG_OFF    59132416ul
#define CNT_OFF    59157504ul
#define DINV_OFF   59182592ul
#define RPTR_OFF   59207680ul
#define COL_OFF    59233024ul
#define W1T_OFF    59458816ul
#define W2T_OFF    61555968ul          // end 62,080,256
// hw (f32, 12.8MB) and h1h (fp16, 6.4MB) reuse the XLO region after gram is done
#define HW_OFF     XLO_OFF
#define H1H_OFF    (XLO_OFF + 12845056ul)

// ---------------- async global->LDS (16B per lane, wave-uniform LDS base) ----
__device__ __forceinline__ void gld_lds16(const void* g, void* l) {
    __builtin_amdgcn_global_load_lds(
        (const __attribute__((address_space(1))) void*)g,
        (__attribute__((address_space(3))) void*)l, 16, 0, 0);
}

// BK=64 tile (hgemm): [row][128B]; 16B slot b holds global k-block b ^ (row&7).
__device__ __forceinline__ half8 frag_read(const char* base, int row, int s, int lane) {
    int b = (s * 4 + (lane >> 4)) ^ (row & 7);
    return *(const half8*)(base + row * 128 + b * 16);
}

#define MF(a, b, c) __builtin_amdgcn_mfma_f32_16x16x32_f16(a, b, c, 0, 0, 0)

// ---------------- x -> (hi, lo) fp16 split ----------------
__global__ __launch_bounds__(256) void conv_split_kernel(const float* __restrict__ x,
        _Float16* __restrict__ xhi, _Float16* __restrict__ xlo) {
    size_t idx = ((size_t)blockIdx.x * 256 + threadIdx.x) * 4;
    float4 v = *(const float4*)(x + idx);
    float vv[4] = {v.x, v.y, v.z, v.w};
    half4 h, l;
#pragma unroll
    for (int j = 0; j < 4; j++) {
        _Float16 hj = (_Float16)vv[j];
        h[j] = hj;
        l[j] = (_Float16)(vv[j] - (float)hj);
    }
    *(half4*)(xhi + idx) = h;
    *(half4*)(xlo + idx) = l;
}

// ---------------- W [K][N] f32 -> Wt [N][K] f16 ----------------
__global__ __launch_bounds__(256) void wtrans_kernel(const float* __restrict__ W,
        _Float16* __restrict__ Wt, int K, int N) {
    __shared__ float tile[64][65];
    int kb = blockIdx.x * 64, nb = blockIdx.y * 64;
    int tid = threadIdx.x;
    int r = tid >> 2, c0 = (tid & 3) * 16;
#pragma unroll
    for (int u = 0; u < 4; u++) {
        float4 v = *(const float4*)(W + (size_t)(kb + r) * N + nb + c0 + u * 4);
        tile[r][c0 + u * 4 + 0] = v.x; tile[r][c0 + u * 4 + 1] = v.y;
        tile[r][c0 + u * 4 + 2] = v.z; tile[r][c0 + u * 4 + 3] = v.w;
    }
    __syncthreads();
    int rn = tid >> 2, ck0 = (tid & 3) * 16;
#pragma unroll
    for (int u = 0; u < 4; u++) {
        half4 o;
#pragma unroll
        for (int j = 0; j < 4; j++) o[j] = (_Float16)tile[ck0 + u * 4 + j][rn];
        *(half4*)(Wt + (size_t)(nb + rn) * K + kb + ck0 + u * 4) = o;
    }
}

// ---------------- sq[i] = sum_c x[i][c]^2 (fp32, exact vs ref) ----------------
__global__ __launch_bounds__(64) void sq_kernel(const float* __restrict__ x,
                                                float* __restrict__ sq) {
    int i = blockIdx.x;
    int t = threadIdx.x;
    const float* row = x + (size_t)i * CDIM;
    float s = 0.f;
#pragma unroll
    for (int k = 0; k < CDIM / 256; k++) {
        float4 v = *(const float4*)(row + (k * 64 + t) * 4);
        s += v.x * v.x + v.y * v.y + v.z * v.z + v.w * v.w;
    }
#pragma unroll
    for (int off = 32; off; off >>= 1) s += __shfl_down(s, off, 64);
    if (t == 0) sq[i] = s;
}

// ---- fused MFMA Gram: upper-tri 256x256 tiles, 2 blocks/CU, row+col top-8 ----
// dot = hi.hi + hi.lo + lo.hi.  Bytes model (r4..r11): wall = staged_bytes /
// ~2.8 TB/s (cache-hierarchy serving rate), schedule-invariant once >=2 blocks/CU
// keep demand up. This config: triangle 325 tiles x 2MB hi+lo staged per side =
// 1.30 GB total (0.53x of r11). 512 threads, 8 waves (wr 0..3 x 64 rows, wc 0..1
// x 128 cols, acc[4][8] -> AGPR). LDS 64KB -> 2 blocks/CU.
// Staging layout (r11-verified): [row][128B] lines; 16B slot b of row holds
// logical (kg,hilo) = b ^ (row&7); hi/lo interleaved via per-lane source select.
// All acc[][] indices compile-time (rule #20).
__global__ __launch_bounds__(512, 2) void gram_topk_mfma(
        const _Float16* __restrict__ xhi, const _Float16* __restrict__ xlo,
        const float* __restrict__ sq,
        float* __restrict__ candv, unsigned short* __restrict__ candi) {
    __shared__ char lds[65536];                              // A 32KB | B 32KB
    float* S = (float*)lds;                                  // [256][33] 33.8KB
    float* topv = (float*)(lds + 33792);                     // [256][9]  9.2KB
    unsigned short* topi = (unsigned short*)(lds + 43008);   // [256][10] 5.1KB
#define TOPV(r, k) topv[(r) * 9 + (k)]
#define TOPI(r, k) topi[(r) * 10 + (k)]

    int tid = threadIdx.x, lane = tid & 63, wave = tid >> 6;   // 8 waves
    int wr = wave >> 1, wc = wave & 1;
    int l15 = lane & 15, kg = lane >> 4;

    // bijective XCD chunking over t-major triangle raster (325 = 8*40 + 5)
    int xcd = blockIdx.x & 7, loc = blockIdx.x >> 3;
    int cnt = (xcd < 5) ? 41 : 40;
    if (loc >= cnt) return;                                    // dead pads
    int raster = (xcd < 5) ? (xcd * 41 + loc) : (5 * 41 + (xcd - 5) * 40 + loc);
    int t = (int)((sqrtf(8.f * (float)raster + 1.f) - 1.f) * 0.5f);
    while ((t + 1) * (t + 2) / 2 <= raster) t++;
    while (t * (t + 1) / 2 > raster) t--;
    int p = raster - t * (t + 1) / 2;                          // p <= t
    size_t i0 = (size_t)p * 256, j0 = (size_t)t * 256;

    f32x4 acc[4][8] = {};

    // staging lane constants (r11 layout): slot (row r_in, block lane&7) holds
    // logical kg2h = (lane&7)^r_in; bit0 selects hi/lo array, bits1+ the k-sub.
    int r_in = lane >> 3;
    int kg2h = (lane & 7) ^ r_in;
    const _Float16* sbase = (kg2h & 1) ? xlo : xhi;
    int koff = (kg2h >> 1) * 8;

#pragma unroll 1
    for (int c = 0; c < 64; c++) {
        int kbase = c * 32 + koff;
#pragma unroll
        for (int g = 0; g < 8; g++) {          // 64 segs (8 rows x 128B), 8/wave
            int sg = wave * 8 + g;
            int tI = sg >> 5, seg = sg & 31;
            size_t row = (tI ? j0 : i0) + (size_t)(seg * 8 + r_in);
            gld_lds16(sbase + row * CDIM + kbase, lds + tI * 32768 + seg * 1024);
        }
        __syncthreads();
        const char* At = lds;
        const char* Bt = lds + 32768;
        half8 ah[4], al[4];
#pragma unroll
        for (int m = 0; m < 4; m++) {
            int row = wr * 64 + m * 16 + l15;
            ah[m] = *(const half8*)(At + row * 128 + ((((kg << 1) | 0) ^ (row & 7)) << 4));
            al[m] = *(const half8*)(At + row * 128 + ((((kg << 1) | 1) ^ (row & 7)) << 4));
        }
#pragma unroll
        for (int n = 0; n < 8; n++) {
            int row = wc * 128 + n * 16 + l15;
            half8 bh = *(const half8*)(Bt + row * 128 + ((((kg << 1) | 0) ^ (row & 7)) << 4));
            half8 bl = *(const half8*)(Bt + row * 128 + ((((kg << 1) | 1) ^ (row & 7)) << 4));
#pragma unroll
            for (int m = 0; m < 4; m++) acc[m][n] = MF(ah[m], bh, acc[m][n]);
#pragma unroll
            for (int m = 0; m < 4; m++) acc[m][n] = MF(al[m], bh, acc[m][n]);
#pragma unroll
            for (int m = 0; m < 4; m++) acc[m][n] = MF(ah[m], bl, acc[m][n]);
        }
        __syncthreads();
    }

    // sq values (guards for the ragged last panel)
    float sqi[4][4];
#pragma unroll
    for (int m = 0; m < 4; m++)
#pragma unroll
        for (int r = 0; r < 4; r++) {
            int gi = (int)i0 + wr * 64 + m * 16 + kg * 4 + r;
            sqi[m][r] = (gi < N_NODES) ? sq[gi] : 0.f;
        }
    float sqj[8];
#pragma unroll
    for (int n = 0; n < 8; n++) {
        int gj = (int)j0 + wc * 128 + n * 16 + l15;
        sqj[n] = (gj < N_NODES) ? sq[gj] : 0.f;
    }

    // init top lists (staging LDS now free)
    if (tid < 256) {
#pragma unroll
        for (int k = 0; k < 8; k++) { TOPV(tid, k) = 3.4e38f; TOPI(tid, k) = 0xFFFF; }
    }

    // ---- row pass: 8 chunks of 32 cols ----
#pragma unroll
    for (int cs = 0; cs < 8; cs++) {
        __syncthreads();
        if (wc == (cs >> 2)) {
            const int n0 = (cs & 3) * 2;
#pragma unroll
            for (int m = 0; m < 4; m++)
#pragma unroll
                for (int nn = 0; nn < 2; nn++)
#pragma unroll
                    for (int r = 0; r < 4; r++) {
                        int row = wr * 64 + m * 16 + kg * 4 + r;
                        float d2 = sqi[m][r] + sqj[n0 + nn] - 2.f * acc[m][n0 + nn][r];
                        S[row * 33 + nn * 16 + l15] = d2;
                    }
        }
        __syncthreads();
        if (tid < 256) {
            int r = tid, gi = (int)i0 + r;
            int cbase = (int)j0 + cs * 32;
#pragma unroll 4
            for (int jj = 0; jj < 32; jj++) {
                int gj = cbase + jj;
                if (gj >= N_NODES || gj == gi) continue;
                float v = S[r * 33 + jj];
                float wv = TOPV(r, 7); int wi = TOPI(r, 7);
                if (v < wv || (v == wv && gj < wi)) {
                    int pos = 7;
                    while (pos > 0) {
                        float pv = TOPV(r, pos - 1); int pi = TOPI(r, pos - 1);
                        if (v < pv || (v == pv && gj < pi)) {
                            TOPV(r, pos) = pv; TOPI(r, pos) = (unsigned short)pi; pos--;
                        } else break;
                    }
                    TOPV(r, pos) = v; TOPI(r, pos) = (unsigned short)gj;
                }
            }
        }
    }
    __syncthreads();
    if (tid < 256) {
        int gi = (int)i0 + tid;
        if (gi < N_NODES) {
#pragma unroll
            for (int k = 0; k < 8; k++) {
                candv[(size_t)gi * NSLOT + t * 8 + k] = TOPV(tid, k);
                candi[(size_t)gi * NSLOT + t * 8 + k] = TOPI(tid, k);
            }
        }
#pragma unroll
        for (int k = 0; k < 8; k++) { TOPV(tid, k) = 3.4e38f; TOPI(tid, k) = 0xFFFF; }
    }

    // ---- column pass (off-diagonal only): 8 chunks of 32 rows ----
    if (p < t) {
#pragma unroll
        for (int ss = 0; ss < 8; ss++) {
            __syncthreads();
            if (wr == (ss >> 1)) {
                const int mb = (ss & 1) * 2;
#pragma unroll
                for (int mm = 0; mm < 2; mm++)
#pragma unroll
                    for (int n = 0; n < 8; n++)
#pragma unroll
                        for (int r = 0; r < 4; r++) {
                            int rl  = mm * 16 + kg * 4 + r;
                            int col = wc * 128 + n * 16 + l15;
                            float d2 = sqi[mb + mm][r] + sqj[n] - 2.f * acc[mb + mm][n][r];
                            S[col * 33 + rl] = d2;
                        }
            }
            __syncthreads();
            if (tid < 256) {
                int cc = tid;
                int rbase = (int)i0 + ss * 32;   // p<t => p<=23 => rows valid
#pragma unroll 4
                for (int jj = 0; jj < 32; jj++) {
                    int gi = rbase + jj;
                    float v = S[cc * 33 + jj];
                    float wv = TOPV(cc, 7); int wi = TOPI(cc, 7);
                    if (v < wv || (v == wv && gi < wi)) {
                        int pos = 7;
                        while (pos > 0) {
                            float pv = TOPV(cc, pos - 1); int pi = TOPI(cc, pos - 1);
                            if (v < pv || (v == pv && gi < pi)) {
                                TOPV(cc, pos) = pv; TOPI(cc, pos) = (unsigned short)pi; pos--;
                            } else break;
                        }
                        TOPV(cc, pos) = v; TOPI(cc, pos) = (unsigned short)gi;
                    }
                }
            }
        }
        __syncthreads();
        if (tid < 256) {
            int gj = (int)j0 + tid;
            if (gj < N_NODES) {
#pragma unroll
                for (int k = 0; k < 8; k++) {
                    candv[(size_t)gj * NSLOT + p * 8 + k] = TOPV(tid, k);
                    candi[(size_t)gj * NSLOT + p * 8 + k] = TOPI(tid, k);
                }
            }
        }
    }
#undef TOPV
#undef TOPI
}

// ------------- merge 25 sorted 8-lists -> knn (wave per node, lex (v,idx)) -----
__global__ __launch_bounds__(256) void merge_topk_kernel(
        const float* __restrict__ candv, const unsigned short* __restrict__ candi,
        int* __restrict__ knn) {
    int node = blockIdx.x * 4 + (threadIdx.x >> 6);
    int lane = threadIdx.x & 63;
    const float* cv = candv + (size_t)node * NSLOT;
    const unsigned short* ci = candi + (size_t)node * NSLOT;
    float v[4]; int ix[4];
#pragma unroll
    for (int u = 0; u < 4; u++) {
        int s = u * 64 + lane;
        bool ok = (s < NSLOT);
        v[u]  = ok ? cv[s] : 3.4e38f;
        ix[u] = ok ? (int)ci[s] : 0x7fffffff;
    }
#pragma unroll 1
    for (int k = 0; k < 8; k++) {
        float bv = v[0]; int bi = ix[0];
#pragma unroll
        for (int u = 1; u < 4; u++)
            if (v[u] < bv || (v[u] == bv && ix[u] < bi)) { bv = v[u]; bi = ix[u]; }
#pragma unroll
        for (int off = 32; off; off >>= 1) {
            float ov = __shfl_xor(bv, off, 64);
            int   oi = __shfl_xor(bi, off, 64);
            if (ov < bv || (ov == bv && oi < bi)) { bv = ov; bi = oi; }
        }
        if (lane == 0) knn[(size_t)node * 8 + k] = bi;
#pragma unroll
        for (int u = 0; u < 4; u++)
            if (ix[u] == bi) { v[u] = 3.4e38f; ix[u] = 0x7fffffff; }
    }
}

// ------------- graph build -------------
__global__ __launch_bounds__(256) void graph_init_kernel(int* deg, int* cnt) {
    int i = blockIdx.x * 256 + threadIdx.x;
    if (i < N_NODES) { deg[i] = 1; cnt[i] = 0; }
}
__global__ __launch_bounds__(256) void deg_count_kernel(const int* __restrict__ knn,
                                                        int* deg) {
    int e = blockIdx.x * 256 + threadIdx.x;
    if (e < N_NODES * 8) atomicAdd(&deg[knn[e]], 1);
}
__global__ __launch_bounds__(256) void dinv_kernel(const int* __restrict__ deg,
                                                   float* __restrict__ dinv) {
    int i = blockIdx.x * 256 + threadIdx.x;
    if (i < N_NODES) dinv[i] = rsqrtf((float)deg[i]);
}
__global__ __launch_bounds__(256) void scan_kernel(const int* __restrict__ deg,
                                                   int* __restrict__ row_ptr) {
    __shared__ int partial[256];
    const int CHUNK = (N_NODES + 255) / 256;
    int tid = threadIdx.x;
    int start = tid * CHUNK;
    int end = start + CHUNK; if (end > N_NODES) end = N_NODES;
    int s = 0;
    for (int i = start; i < end; i++) s += deg[i];
    partial[tid] = s;
    __syncthreads();
    if (tid == 0) {
        int run = 0;
        for (int k = 0; k < 256; k++) { int v = partial[k]; partial[k] = run; run += v; }
        row_ptr[N_NODES] = run;
    }
    __syncthreads();
    int run = partial[tid];
    for (int i = start; i < end; i++) { row_ptr[i] = run; run += deg[i]; }
}
__global__ __launch_bounds__(256) void scatter_kernel(const int* __restrict__ knn,
        const int* __restrict__ row_ptr, int* cnt, int* __restrict__ col) {
    int i = blockIdx.x * 256 + threadIdx.x;
    if (i >= N_NODES) return;
    int ptr = row_ptr[i] + atomicAdd(&cnt[i], 1);
    col[ptr] = i;                                   // self-loop
#pragma unroll
    for (int j = 0; j < 8; j++) {
        int d = knn[(size_t)i * 8 + j];
        int q = row_ptr[d] + atomicAdd(&cnt[d], 1);
        col[q] = i;
    }
}

// ------------- fp16 MFMA GEMM  C[M,N] = A[M,K] @ Bt[N,K]^T  (f32 out) --------
__global__ __launch_bounds__(256) void hgemm_nt_kernel(
        const _Float16* __restrict__ A, const _Float16* __restrict__ Bt,
        float* __restrict__ C, int M, int N, int K) {
    __shared__ char Alds[16384], Blds[16384];
    int tid = threadIdx.x, lane = tid & 63, wave = tid >> 6;
    int wr = wave >> 1, wc = wave & 1;
    int l15 = lane & 15, kg = lane >> 4;
    int nt = N >> 7;
    int i0 = (blockIdx.x / nt) * 128, j0 = (blockIdx.x % nt) * 128;
    f32x4 acc[4][4] = {};

#pragma unroll 1
    for (int kk = 0; kk < K; kk += 64) {
        __syncthreads();
#pragma unroll
        for (int g = 0; g < 4; g++) {
            int R = wave * 32 + g * 8;
            int swzk = ((lane & 7) ^ (lane >> 3)) << 3;
            const _Float16* ga = A + (size_t)(i0 + R + (lane >> 3)) * K + kk + swzk;
            gld_lds16(ga, Alds + R * 128);
            const _Float16* gb = Bt + (size_t)(j0 + R + (lane >> 3)) * K + kk + swzk;
            gld_lds16(gb, Blds + R * 128);
        }
        __syncthreads();
#pragma unroll
        for (int s = 0; s < 2; s++) {
            half8 a[4], b[4];
#pragma unroll
            for (int m = 0; m < 4; m++) a[m] = frag_read(Alds, wr * 64 + m * 16 + l15, s, lane);
#pragma unroll
            for (int n = 0; n < 4; n++) b[n] = frag_read(Blds, wc * 64 + n * 16 + l15, s, lane);
#pragma unroll
            for (int m = 0; m < 4; m++)
#pragma unroll
                for (int n = 0; n < 4; n++)
                    acc[m][n] = __builtin_amdgcn_mfma_f32_16x16x32_f16(a[m], b[n], acc[m][n], 0, 0, 0);
        }
    }
#pragma unroll
    for (int m = 0; m < 4; m++)
#pragma unroll
        for (int n = 0; n < 4; n++)
#pragma unroll
            for (int r = 0; r < 4; r++) {
                int row = i0 + wr * 64 + m * 16 + kg * 4 + r;
                int colj = j0 + wc * 64 + n * 16 + l15;
                C[(size_t)row * N + colj] = acc[m][n][r];
            }
}

// ------------- GCN aggregation: out[d] = relu(dinv[d]*sum hw[s]*dinv[s] + b) ---
template <bool HALF>
__global__ __launch_bounds__(256) void aggregate_kernel(
        const float* __restrict__ hw, const int* __restrict__ row_ptr,
        const int* __restrict__ col, const float* __restrict__ dinv,
        const float* __restrict__ bias, void* __restrict__ outp) {
    int node = blockIdx.x * 4 + (threadIdx.x >> 6);
    int lane = threadIdx.x & 63;
    int e0 = row_ptr[node], e1 = row_ptr[node + 1];
    float4 acc0 = {0.f, 0.f, 0.f, 0.f}, acc1 = {0.f, 0.f, 0.f, 0.f};
    for (int e = e0; e < e1; e++) {
        int s = col[e];
        float w = dinv[s];
        const float* hr = hw + (size_t)s * ODIM;
        float4 v0 = *(const float4*)(hr + lane * 4);
        float4 v1 = *(const float4*)(hr + 256 + lane * 4);
        acc0.x = fmaf(w, v0.x, acc0.x); acc0.y = fmaf(w, v0.y, acc0.y);
        acc0.z = fmaf(w, v0.z, acc0.z); acc0.w = fmaf(w, v0.w, acc0.w);
        acc1.x = fmaf(w, v1.x, acc1.x); acc1.y = fmaf(w, v1.y, acc1.y);
        acc1.z = fmaf(w, v1.z, acc1.z); acc1.w = fmaf(w, v1.w, acc1.w);
    }
    float wd = dinv[node];
    float4 b0 = *(const float4*)(bias + lane * 4);
    float4 b1 = *(const float4*)(bias + 256 + lane * 4);
    float o[8];
    o[0] = fmaxf(fmaf(acc0.x, wd, b0.x), 0.f);
    o[1] = fmaxf(fmaf(acc0.y, wd, b0.y), 0.f);
    o[2] = fmaxf(fmaf(acc0.z, wd, b0.z), 0.f);
    o[3] = fmaxf(fmaf(acc0.w, wd, b0.w), 0.f);
    o[4] = fmaxf(fmaf(acc1.x, wd, b1.x), 0.f);
    o[5] = fmaxf(fmaf(acc1.y, wd, b1.y), 0.f);
    o[6] = fmaxf(fmaf(acc1.z, wd, b1.z), 0.f);
    o[7] = fmaxf(fmaf(acc1.w, wd, b1.w), 0.f);
    if (HALF) {
        _Float16* out = (_Float16*)outp;
        half4 h0, h1;
#pragma unroll
        for (int j = 0; j < 4; j++) { h0[j] = (_Float16)o[j]; h1[j] = (_Float16)o[4 + j]; }
        *(half4*)(out + (size_t)node * ODIM + lane * 4)       = h0;
        *(half4*)(out + (size_t)node * ODIM + 256 + lane * 4) = h1;
    } else {
        float* out = (float*)outp;
        float4 f0 = {o[0], o[1], o[2], o[3]}, f1 = {o[4], o[5], o[6], o[7]};
        *(float4*)(out + (size_t)node * ODIM + lane * 4)       = f0;
        *(float4*)(out + (size_t)node * ODIM + 256 + lane * 4) = f1;
    }
}

extern "C" void kernel_launch(void* const* d_in, const int* in_sizes, int n_in,
                              void* d_out, int out_size, void* d_ws, size_t ws_size,
                              hipStream_t stream) {
    const float* x  = (const float*)d_in[0];
    const float* W1 = (const float*)d_in[1];
    const float* b1 = (const float*)d_in[2];
    const float* W2 = (const float*)d_in[3];
    const float* b2 = (const float*)d_in[4];
    float* out = (float*)d_out;
    char* ws = (char*)d_ws;

    _Float16* xhi  = (_Float16*)(ws + XHI_OFF);
    _Float16* xlo  = (_Float16*)(ws + XLO_OFF);
    float* candv   = (float*)(ws + CANDV_OFF);
    unsigned short* candi = (unsigned short*)(ws + CANDI_OFF);
    float* sq      = (float*)(ws + SQ_OFF);
    int*   knn     = (int*)  (ws + KNN_OFF);
    int*   deg     = (int*)  (ws + DEG_OFF);
    int*   cnt     = (int*)  (ws + CNT_OFF);
    float* dinv    = (float*)(ws + DINV_OFF);
    int*   row_ptr = (int*)  (ws + RPTR_OFF);
    int*   col     = (int*)  (ws + COL_OFF);
    _Float16* w1t  = (_Float16*)(ws + W1T_OFF);
    _Float16* w2t  = (_Float16*)(ws + W2T_OFF);
    float* hw      = (float*)(ws + HW_OFF);       // reuses xlo region (post-gram)
    _Float16* h1h  = (_Float16*)(ws + H1H_OFF);   // reuses xlo region (post-gram)

    conv_split_kernel<<<12544, 256, 0, stream>>>(x, xhi, xlo);
    sq_kernel<<<N_NODES, 64, 0, stream>>>(x, sq);
    wtrans_kernel<<<dim3(CDIM / 64, ODIM / 64), 256, 0, stream>>>(W1, w1t, CDIM, ODIM);
    wtrans_kernel<<<dim3(ODIM / 64, ODIM / 64), 256, 0, stream>>>(W2, w2t, ODIM, ODIM);

    gram_topk_mfma<<<GRID_G, 512, 0, stream>>>(xhi, xlo, sq, candv, candi);
    merge_topk_kernel<<<N_NODES / 4, 256, 0, stream>>>(candv, candi, knn);

    graph_init_kernel<<<(N_NODES + 255) / 256, 256, 0, stream>>>(deg, cnt);
    deg_count_kernel<<<(N_NODES * 8) / 256, 256, 0, stream>>>(knn, deg);
    dinv_kernel<<<(N_NODES + 255) / 256, 256, 0, stream>>>(deg, dinv);
    scan_kernel<<<1, 256, 0, stream>>>(deg, row_ptr);
    scatter_kernel<<<(N_NODES + 255) / 256, 256, 0, stream>>>(knn, row_ptr, cnt, col);

    hgemm_nt_kernel<<<(N_NODES / 128) * (ODIM / 128), 256, 0, stream>>>(xhi, w1t, hw, N_NODES, ODIM, CDIM);
    aggregate_kernel<true><<<N_NODES / 4, 256, 0, stream>>>(hw, row_ptr, col, dinv, b1, (void*)h1h);
    hgemm_nt_kernel<<<(N_NODES / 128) * (ODIM / 128), 256, 0, stream>>>(h1h, w2t, hw, N_NODES, ODIM, ODIM);
    aggregate_kernel<false><<<N_NODES / 4, 256, 0, stream>>>(hw, row_ptr, col, dinv, b2, (void*)out);
}

// Round 13
// 1197.497 us; speedup vs baseline: 1.4623x; 1.4623x over previous
//
#include <hip/hip_runtime.h>

typedef __attribute__((ext_vector_type(8))) _Float16 half8;
typedef __attribute__((ext_vector_type(4))) _Float16 half4;
typedef __attribute__((ext_vector_type(4))) float f32x4;

#define N_NODES 6272
#define CDIM    2048
#define ODIM    512
#define NPAN    49       // 6272 / 128 node panels
#define NSLOT   392      // 49 panels * 8 candidates per node
#define GRID_G  1232     // 8 x 154 (1225 live triangle tiles + 7 dead)
#define GATE    0.6f     // refine if approx gap(8th,9th) < GATE (err sigma ~0.03)

// ---------------- workspace layout (bytes) ----------------
#define XHI_OFF    0ul                 // 25,690,112
#define CANDV_OFF  25690112ul          // 6272*392*4 = 9,834,496
#define CANDI_OFF  35524608ul          // 6272*392*2 = 4,917,248
#define SQ_OFF     40441856ul          // 25,088
#define KNN_OFF    40466944ul          // 200,704
#define C16_OFF    40667648ul          // 6272*16*4 = 401,408
#define V16_OFF    41069056ul          // 401,408
#define DEG_OFF    41470464ul
#define CNT_OFF    41495552ul
#define DINV_OFF   41520640ul
#define RPTR_OFF   41545728ul
#define COL_OFF    41571072ul          // 225,792
#define W1T_OFF    41796864ul          // 2,097,152
#define W2T_OFF    43894016ul          // 524,288 -> 44,418,304
// hw (f32 12.8MB) reuses CANDV+CANDI (dead after refine); h1h after W2T
#define HW_OFF     CANDV_OFF
#define H1H_OFF    44418304ul          // 6.4MB -> end 50.8MB

// ---------------- async global->LDS (16B per lane, wave-uniform LDS base) ----
__device__ __forceinline__ void gld_lds16(const void* g, void* l) {
    __builtin_amdgcn_global_load_lds(
        (const __attribute__((address_space(1))) void*)g,
        (__attribute__((address_space(3))) void*)l, 16, 0, 0);
}

// BK=64 tile: [row][128B]; 16B slot b holds global k-block b ^ (row&7).
__device__ __forceinline__ half8 frag_read(const char* base, int row, int s, int lane) {
    int b = (s * 4 + (lane >> 4)) ^ (row & 7);
    return *(const half8*)(base + row * 128 + b * 16);
}

#define MF(a, b, c) __builtin_amdgcn_mfma_f32_16x16x32_f16(a, b, c, 0, 0, 0)

// ---------------- fused: x -> xhi (fp16) and sq (fp32) in one pass ----------------
__global__ __launch_bounds__(64) void conv_sq_kernel(const float* __restrict__ x,
        _Float16* __restrict__ xhi, float* __restrict__ sq) {
    int i = blockIdx.x;
    int t = threadIdx.x;
    const float* row = x + (size_t)i * CDIM;
    _Float16* hrow = xhi + (size_t)i * CDIM;
    float s = 0.f;
#pragma unroll
    for (int k = 0; k < 8; k++) {
        float4 v = *(const float4*)(row + (k * 64 + t) * 4);
        half4 h;
        h[0] = (_Float16)v.x; h[1] = (_Float16)v.y;
        h[2] = (_Float16)v.z; h[3] = (_Float16)v.w;
        *(half4*)(hrow + (k * 64 + t) * 4) = h;
        s += v.x * v.x + v.y * v.y + v.z * v.z + v.w * v.w;
    }
#pragma unroll
    for (int off = 32; off; off >>= 1) s += __shfl_down(s, off, 64);
    if (t == 0) sq[i] = s;
}

// ---------------- W [K][N] f32 -> Wt [N][K] f16 ----------------
__global__ __launch_bounds__(256) void wtrans_kernel(const float* __restrict__ W,
        _Float16* __restrict__ Wt, int K, int N) {
    __shared__ float tile[64][65];
    int kb = blockIdx.x * 64, nb = blockIdx.y * 64;
    int tid = threadIdx.x;
    int r = tid >> 2, c0 = (tid & 3) * 16;
#pragma unroll
    for (int u = 0; u < 4; u++) {
        float4 v = *(const float4*)(W + (size_t)(kb + r) * N + nb + c0 + u * 4);
        tile[r][c0 + u * 4 + 0] = v.x; tile[r][c0 + u * 4 + 1] = v.y;
        tile[r][c0 + u * 4 + 2] = v.z; tile[r][c0 + u * 4 + 3] = v.w;
    }
    __syncthreads();
    int rn = tid >> 2, ck0 = (tid & 3) * 16;
#pragma unroll
    for (int u = 0; u < 4; u++) {
        half4 o;
#pragma unroll
        for (int j = 0; j < 4; j++) o[j] = (_Float16)tile[ck0 + u * 4 + j][rn];
        *(half4*)(Wt + (size_t)(nb + rn) * K + kb + ck0 + u * 4) = o;
    }
}

// ---- hi-only MFMA Gram SCREEN: upper-tri 128x128 tiles, 4+ blocks/CU ----
// approx d2 (hi.hi only, err sigma ~0.03 on d2~4096); exact repair in refine_kernel.
// Structure = r11's verified kernel minus lo: BK=64, 32 chunks, 256 thr (2x2 waves),
// 32KB LDS (S/topv/topi overlay), triangle raster + dual row/col top-8.
__global__ __launch_bounds__(256, 4) void gram_screen(
        const _Float16* __restrict__ xhi, const float* __restrict__ sq,
        float* __restrict__ candv, unsigned short* __restrict__ candi) {
    __shared__ char lds[32768];
    float* S = (float*)lds;                                  // [128][33] 16.9KB
    float* topv = (float*)(lds + 16896);                     // [128][9]  4.6KB
    unsigned short* topi = (unsigned short*)(lds + 21504);   // [128][10] 2.6KB
#define TOPV(r, k) topv[(r) * 9 + (k)]
#define TOPI(r, k) topi[(r) * 10 + (k)]

    int tid = threadIdx.x, lane = tid & 63, wave = tid >> 6;   // 4 waves
    int wr = wave >> 1, wc = wave & 1;
    int l15 = lane & 15, kg = lane >> 4;

    // bijective XCD chunking over t-major triangle raster (1225 = 8*153 + 1)
    int xcd = blockIdx.x & 7, loc = blockIdx.x >> 3;
    if (xcd != 0 && loc >= 153) return;                        // dead pads
    int raster = (xcd == 0) ? loc : (154 + (xcd - 1) * 153 + loc);
    int t = (int)((sqrtf(8.f * (float)raster + 1.f) - 1.f) * 0.5f);
    while ((t + 1) * (t + 2) / 2 <= raster) t++;
    while (t * (t + 1) / 2 > raster) t--;
    int p = raster - t * (t + 1) / 2;                          // p <= t
    size_t i0 = (size_t)p * 128, j0 = (size_t)t * 128;

    f32x4 acc[4][4] = {};

    int r_in = lane >> 3;                  // 0..7
    int skb = (lane & 7) ^ r_in;           // pre-swizzled 16B block (matches frag_read)

#pragma unroll 1
    for (int c = 0; c < 32; c++) {
        int kk = c * 64;
#pragma unroll
        for (int g = 0; g < 8; g++) {      // 32 segs (8 rows x 128B), 8 per wave
            int sg = wave * 8 + g;
            int tI = sg >> 4, seg = sg & 15;
            size_t row = (tI ? j0 : i0) + (size_t)(seg * 8 + r_in);
            gld_lds16(xhi + row * CDIM + kk + skb * 8, lds + tI * 16384 + seg * 1024);
        }
        __syncthreads();
#pragma unroll
        for (int s = 0; s < 2; s++) {
            half8 a4[4];
#pragma unroll
            for (int m = 0; m < 4; m++)
                a4[m] = frag_read(lds, wr * 64 + m * 16 + l15, s, lane);
#pragma unroll
            for (int n = 0; n < 4; n++) {
                half8 b = frag_read(lds + 16384, wc * 64 + n * 16 + l15, s, lane);
#pragma unroll
                for (int m = 0; m < 4; m++) acc[m][n] = MF(a4[m], b, acc[m][n]);
            }
        }
        __syncthreads();
    }

    // sq values (6272 = 49*128: no guards needed)
    float sqi[4][4];
#pragma unroll
    for (int m = 0; m < 4; m++)
#pragma unroll
        for (int r = 0; r < 4; r++)
            sqi[m][r] = sq[(int)i0 + wr * 64 + m * 16 + kg * 4 + r];
    float sqj[4];
#pragma unroll
    for (int n = 0; n < 4; n++)
        sqj[n] = sq[(int)j0 + wc * 64 + n * 16 + l15];

    if (tid < 128) {
#pragma unroll
        for (int k = 0; k < 8; k++) { TOPV(tid, k) = 3.4e38f; TOPI(tid, k) = 0xFFFF; }
    }

    // ---- row pass: 4 chunks of 32 cols ----
#pragma unroll
    for (int cs = 0; cs < 4; cs++) {
        __syncthreads();
        if (wc == (cs >> 1)) {
            const int n0 = (cs & 1) * 2;
#pragma unroll
            for (int m = 0; m < 4; m++)
#pragma unroll
                for (int nn = 0; nn < 2; nn++)
#pragma unroll
                    for (int r = 0; r < 4; r++) {
                        int row = wr * 64 + m * 16 + kg * 4 + r;
                        float d2 = sqi[m][r] + sqj[n0 + nn] - 2.f * acc[m][n0 + nn][r];
                        S[row * 33 + nn * 16 + l15] = d2;
                    }
        }
        __syncthreads();
        if (tid < 128) {
            int r = tid, gi = (int)i0 + r;
            int cbase = (int)j0 + cs * 32;
#pragma unroll 4
            for (int jj = 0; jj < 32; jj++) {
                int gj = cbase + jj;
                if (gj == gi) continue;
                float v = S[r * 33 + jj];
                float wv = TOPV(r, 7); int wi = TOPI(r, 7);
                if (v < wv || (v == wv && gj < wi)) {
                    int pos = 7;
                    while (pos > 0) {
                        float pv = TOPV(r, pos - 1); int pi = TOPI(r, pos - 1);
                        if (v < pv || (v == pv && gj < pi)) {
                            TOPV(r, pos) = pv; TOPI(r, pos) = (unsigned short)pi; pos--;
                        } else break;
                    }
                    TOPV(r, pos) = v; TOPI(r, pos) = (unsigned short)gj;
                }
            }
        }
    }
    __syncthreads();
    if (tid < 128) {
        int gi = (int)i0 + tid;
#pragma unroll
        for (int k = 0; k < 8; k++) {
            candv[(size_t)gi * NSLOT + t * 8 + k] = TOPV(tid, k);
            candi[(size_t)gi * NSLOT + t * 8 + k] = TOPI(tid, k);
        }
#pragma unroll
        for (int k = 0; k < 8; k++) { TOPV(tid, k) = 3.4e38f; TOPI(tid, k) = 0xFFFF; }
    }

    // ---- column pass (off-diagonal only): 4 chunks of 32 rows ----
    if (p < t) {
#pragma unroll
        for (int ss = 0; ss < 4; ss++) {
            __syncthreads();
            if (wr == (ss >> 1)) {
                const int mb = (ss & 1) * 2;
#pragma unroll
                for (int mm = 0; mm < 2; mm++)
#pragma unroll
                    for (int n = 0; n < 4; n++)
#pragma unroll
                        for (int r = 0; r < 4; r++) {
                            int rl  = mm * 16 + kg * 4 + r;
                            int col = wc * 64 + n * 16 + l15;
                            float d2 = sqi[mb + mm][r] + sqj[n] - 2.f * acc[mb + mm][n][r];
                            S[col * 33 + rl] = d2;
                        }
            }
            __syncthreads();
            if (tid < 128) {
                int cc = tid;
                int rbase = (int)i0 + ss * 32;
#pragma unroll 4
                for (int jj = 0; jj < 32; jj++) {
                    int gi = rbase + jj;
                    float v = S[cc * 33 + jj];
                    float wv = TOPV(cc, 7); int wi = TOPI(cc, 7);
                    if (v < wv || (v == wv && gi < wi)) {
                        int pos = 7;
                        while (pos > 0) {
                            float pv = TOPV(cc, pos - 1); int pi = TOPI(cc, pos - 1);
                            if (v < pv || (v == pv && gi < pi)) {
                                TOPV(cc, pos) = pv; TOPI(cc, pos) = (unsigned short)pi; pos--;
                            } else break;
                        }
                        TOPV(cc, pos) = v; TOPI(cc, pos) = (unsigned short)gi;
                    }
                }
            }
        }
        __syncthreads();
        if (tid < 128) {
            int gj = (int)j0 + tid;
#pragma unroll
            for (int k = 0; k < 8; k++) {
                candv[(size_t)gj * NSLOT + p * 8 + k] = TOPV(tid, k);
                candi[(size_t)gj * NSLOT + p * 8 + k] = TOPI(tid, k);
            }
        }
    }
#undef TOPV
#undef TOPI
}

// ------------- merge 49 lists -> approx top-16 per node (wave/node, lex) -------
__global__ __launch_bounds__(256) void merge_topk16_kernel(
        const float* __restrict__ candv, const unsigned short* __restrict__ candi,
        int* __restrict__ cand16, float* __restrict__ val16) {
    int node = blockIdx.x * 4 + (threadIdx.x >> 6);
    int lane = threadIdx.x & 63;
    const float* cv = candv + (size_t)node * NSLOT;
    const unsigned short* ci = candi + (size_t)node * NSLOT;
    float v[7]; int ix[7];
#pragma unroll
    for (int u = 0; u < 7; u++) {
        int s = u * 64 + lane;
        bool ok = (s < NSLOT);
        v[u]  = ok ? cv[s] : 3.4e38f;
        ix[u] = ok ? (int)ci[s] : 0x7fffffff;
    }
#pragma unroll 1
    for (int k = 0; k < 16; k++) {
        float bv = v[0]; int bi = ix[0];
#pragma unroll
        for (int u = 1; u < 7; u++)
            if (v[u] < bv || (v[u] == bv && ix[u] < bi)) { bv = v[u]; bi = ix[u]; }
#pragma unroll
        for (int off = 32; off; off >>= 1) {
            float ov = __shfl_xor(bv, off, 64);
            int   oi = __shfl_xor(bi, off, 64);
            if (ov < bv || (ov == bv && oi < bi)) { bv = ov; bi = oi; }
        }
        if (lane == 0) { cand16[node * 16 + k] = bi; val16[node * 16 + k] = bv; }
#pragma unroll
        for (int u = 0; u < 7; u++)
            if (ix[u] == bi) { v[u] = 3.4e38f; ix[u] = 0x7fffffff; }
    }
}

// ------------- exact fp32 refine of approx top-16 -> knn top-8 (wave/node) -----
// Skip (approx set provably exact) when gap(8th,9th) > GATE >> 2*err.
__global__ __launch_bounds__(256) void refine_kernel(
        const float* __restrict__ x, const float* __restrict__ sq,
        const int* __restrict__ cand16, const float* __restrict__ val16,
        int* __restrict__ knn) {
    int node = blockIdx.x * 4 + (threadIdx.x >> 6);
    int lane = threadIdx.x & 63;
    const int* ci = cand16 + node * 16;
    const float* vi = val16 + node * 16;
    if (vi[8] - vi[7] > GATE) {
        if (lane < 8) knn[(size_t)node * 8 + lane] = ci[lane];
        return;
    }
    const float* xi = x + (size_t)node * CDIM;
    float4 a[8];
#pragma unroll
    for (int g = 0; g < 8; g++) a[g] = *(const float4*)(xi + (g * 64 + lane) * 4);
    float sqi = sq[node];
    float myv = 3.4e38f; int myi = 0x7fffffff;
#pragma unroll 1
    for (int c = 0; c < 16; c++) {
        int j = ci[c];
        const float* xj = x + (size_t)j * CDIM;
        float s = 0.f;
#pragma unroll
        for (int g = 0; g < 8; g++) {
            float4 b = *(const float4*)(xj + (g * 64 + lane) * 4);
            s = fmaf(a[g].x, b.x, s); s = fmaf(a[g].y, b.y, s);
            s = fmaf(a[g].z, b.z, s); s = fmaf(a[g].w, b.w, s);
        }
#pragma unroll
        for (int off = 32; off; off >>= 1) s += __shfl_down(s, off, 64);
        float d2 = sqi + sq[j] - 2.f * s;
        d2 = __shfl(d2, 0, 64);
        if (lane == c) { myv = d2; myi = j; }
    }
#pragma unroll 1
    for (int k = 0; k < 8; k++) {
        float bv = myv; int bi = myi;
#pragma unroll
        for (int off = 8; off; off >>= 1) {      // butterfly over lanes 0..15
            float ov = __shfl_xor(bv, off, 64);
            int   oi = __shfl_xor(bi, off, 64);
            if (ov < bv || (ov == bv && oi < bi)) { bv = ov; bi = oi; }
        }
        bv = __shfl(bv, lane & 15, 64); bi = __shfl(bi, lane & 15, 64);
        if (lane == 0) knn[(size_t)node * 8 + k] = bi;
        if (myi == bi) { myv = 3.4e38f; myi = 0x7fffffff; }
    }
}

// ------------- graph build -------------
__global__ __launch_bounds__(256) void graph_init_kernel(int* deg, int* cnt) {
    int i = blockIdx.x * 256 + threadIdx.x;
    if (i < N_NODES) { deg[i] = 1; cnt[i] = 0; }
}
__global__ __launch_bounds__(256) void deg_count_kernel(const int* __restrict__ knn,
                                                        int* deg) {
    int e = blockIdx.x * 256 + threadIdx.x;
    if (e < N_NODES * 8) atomicAdd(&deg[knn[e]], 1);
}
__global__ __launch_bounds__(256) void dinv_kernel(const int* __restrict__ deg,
                                                   float* __restrict__ dinv) {
    int i = blockIdx.x * 256 + threadIdx.x;
    if (i < N_NODES) dinv[i] = rsqrtf((float)deg[i]);
}
__global__ __launch_bounds__(256) void scan_kernel(const int* __restrict__ deg,
                                                   int* __restrict__ row_ptr) {
    __shared__ int partial[256];
    const int CHUNK = (N_NODES + 255) / 256;
    int tid = threadIdx.x;
    int start = tid * CHUNK;
    int end = start + CHUNK; if (end > N_NODES) end = N_NODES;
    int s = 0;
    for (int i = start; i < end; i++) s += deg[i];
    partial[tid] = s;
    __syncthreads();
    if (tid == 0) {
        int run = 0;
        for (int k = 0; k < 256; k++) { int v = partial[k]; partial[k] = run; run += v; }
        row_ptr[N_NODES] = run;
    }
    __syncthreads();
    int run = partial[tid];
    for (int i = start; i < end; i++) { row_ptr[i] = run; run += deg[i]; }
}
__global__ __launch_bounds__(256) void scatter_kernel(const int* __restrict__ knn,
        const int* __restrict__ row_ptr, int* cnt, int* __restrict__ col) {
    int i = blockIdx.x * 256 + threadIdx.x;
    if (i >= N_NODES) return;
    int ptr = row_ptr[i] + atomicAdd(&cnt[i], 1);
    col[ptr] = i;                                   // self-loop
#pragma unroll
    for (int j = 0; j < 8; j++) {
        int d = knn[(size_t)i * 8 + j];
        int q = row_ptr[d] + atomicAdd(&cnt[d], 1);
        col[q] = i;
    }
}

// ------------- fp16 MFMA GEMM  C[M,N] = A[M,K] @ Bt[N,K]^T  (f32 out) --------
__global__ __launch_bounds__(256) void hgemm_nt_kernel(
        const _Float16* __restrict__ A, const _Float16* __restrict__ Bt,
        float* __restrict__ C, int M, int N, int K) {
    __shared__ char Alds[16384], Blds[16384];
    int tid = threadIdx.x, lane = tid & 63, wave = tid >> 6;
    int wr = wave >> 1, wc = wave & 1;
    int l15 = lane & 15, kg = lane >> 4;
    int nt = N >> 7;
    int i0 = (blockIdx.x / nt) * 128, j0 = (blockIdx.x % nt) * 128;
    f32x4 acc[4][4] = {};

#pragma unroll 1
    for (int kk = 0; kk < K; kk += 64) {
        __syncthreads();
#pragma unroll
        for (int g = 0; g < 4; g++) {
            int R = wave * 32 + g * 8;
            int swzk = ((lane & 7) ^ (lane >> 3)) << 3;
            const _Float16* ga = A + (size_t)(i0 + R + (lane >> 3)) * K + kk + swzk;
            gld_lds16(ga, Alds + R * 128);
            const _Float16* gb = Bt + (size_t)(j0 + R + (lane >> 3)) * K + kk + swzk;
            gld_lds16(gb, Blds + R * 128);
        }
        __syncthreads();
#pragma unroll
        for (int s = 0; s < 2; s++) {
            half8 a[4], b[4];
#pragma unroll
            for (int m = 0; m < 4; m++) a[m] = frag_read(Alds, wr * 64 + m * 16 + l15, s, lane);
#pragma unroll
            for (int n = 0; n < 4; n++) b[n] = frag_read(Blds, wc * 64 + n * 16 + l15, s, lane);
#pragma unroll
            for (int m = 0; m < 4; m++)
#pragma unroll
                for (int n = 0; n < 4; n++)
                    acc[m][n] = __builtin_amdgcn_mfma_f32_16x16x32_f16(a[m], b[n], acc[m][n], 0, 0, 0);
        }
    }
#pragma unroll
    for (int m = 0; m < 4; m++)
#pragma unroll
        for (int n = 0; n < 4; n++)
#pragma unroll
            for (int r = 0; r < 4; r++) {
                int row = i0 + wr * 64 + m * 16 + kg * 4 + r;
                int colj = j0 + wc * 64 + n * 16 + l15;
                C[(size_t)row * N + colj] = acc[m][n][r];
            }
}

// ------------- GCN aggregation: out[d] = relu(dinv[d]*sum hw[s]*dinv[s] + b) ---
template <bool HALF>
__global__ __launch_bounds__(256) void aggregate_kernel(
        const float* __restrict__ hw, const int* __restrict__ row_ptr,
        const int* __restrict__ col, const float* __restrict__ dinv,
        const float* __restrict__ bias, void* __restrict__ outp) {
    int node = blockIdx.x * 4 + (threadIdx.x >> 6);
    int lane = threadIdx.x & 63;
    int e0 = row_ptr[node], e1 = row_ptr[node + 1];
    float4 acc0 = {0.f, 0.f, 0.f, 0.f}, acc1 = {0.f, 0.f, 0.f, 0.f};
    for (int e = e0; e < e1; e++) {
        int s = col[e];
        float w = dinv[s];
        const float* hr = hw + (size_t)s * ODIM;
        float4 v0 = *(const float4*)(hr + lane * 4);
        float4 v1 = *(const float4*)(hr + 256 + lane * 4);
        acc0.x = fmaf(w, v0.x, acc0.x); acc0.y = fmaf(w, v0.y, acc0.y);
        acc0.z = fmaf(w, v0.z, acc0.z); acc0.w = fmaf(w, v0.w, acc0.w);
        acc1.x = fmaf(w, v1.x, acc1.x); acc1.y = fmaf(w, v1.y, acc1.y);
        acc1.z = fmaf(w, v1.z, acc1.z); acc1.w = fmaf(w, v1.w, acc1.w);
    }
    float wd = dinv[node];
    float4 b0 = *(const float4*)(bias + lane * 4);
    float4 b1 = *(const float4*)(bias + 256 + lane * 4);
    float o[8];
    o[0] = fmaxf(fmaf(acc0.x, wd, b0.x), 0.f);
    o[1] = fmaxf(fmaf(acc0.y, wd, b0.y), 0.f);
    o[2] = fmaxf(fmaf(acc0.z, wd, b0.z), 0.f);
    o[3] = fmaxf(fmaf(acc0.w, wd, b0.w), 0.f);
    o[4] = fmaxf(fmaf(acc1.x, wd, b1.x), 0.f);
    o[5] = fmaxf(fmaf(acc1.y, wd, b1.y), 0.f);
    o[6] = fmaxf(fmaf(acc1.z, wd, b1.z), 0.f);
    o[7] = fmaxf(fmaf(acc1.w, wd, b1.w), 0.f);
    if (HALF) {
        _Float16* out = (_Float16*)outp;
        half4 h0, h1;
#pragma unroll
        for (int j = 0; j < 4; j++) { h0[j] = (_Float16)o[j]; h1[j] = (_Float16)o[4 + j]; }
        *(half4*)(out + (size_t)node * ODIM + lane * 4)       = h0;
        *(half4*)(out + (size_t)node * ODIM + 256 + lane * 4) = h1;
    } else {
        float* out = (float*)outp;
        float4 f0 = {o[0], o[1], o[2], o[3]}, f1 = {o[4], o[5], o[6], o[7]};
        *(float4*)(out + (size_t)node * ODIM + lane * 4)       = f0;
        *(float4*)(out + (size_t)node * ODIM + 256 + lane * 4) = f1;
    }
}

extern "C" void kernel_launch(void* const* d_in, const int* in_sizes, int n_in,
                              void* d_out, int out_size, void* d_ws, size_t ws_size,
                              hipStream_t stream) {
    const float* x  = (const float*)d_in[0];
    const float* W1 = (const float*)d_in[1];
    const float* b1 = (const float*)d_in[2];
    const float* W2 = (const float*)d_in[3];
    const float* b2 = (const float*)d_in[4];
    float* out = (float*)d_out;
    char* ws = (char*)d_ws;

    _Float16* xhi  = (_Float16*)(ws + XHI_OFF);
    float* candv   = (float*)(ws + CANDV_OFF);
    unsigned short* candi = (unsigned short*)(ws + CANDI_OFF);
    float* sq      = (float*)(ws + SQ_OFF);
    int*   knn     = (int*)  (ws + KNN_OFF);
    int*   cand16  = (int*)  (ws + C16_OFF);
    float* val16   = (float*)(ws + V16_OFF);
    int*   deg     = (int*)  (ws + DEG_OFF);
    int*   cnt     = (int*)  (ws + CNT_OFF);
    float* dinv    = (float*)(ws + DINV_OFF);
    int*   row_ptr = (int*)  (ws + RPTR_OFF);
    int*   col     = (int*)  (ws + COL_OFF);
    _Float16* w1t  = (_Float16*)(ws + W1T_OFF);
    _Float16* w2t  = (_Float16*)(ws + W2T_OFF);
    float* hw      = (float*)(ws + HW_OFF);       // reuses candv/candi (post-refine)
    _Float16* h1h  = (_Float16*)(ws + H1H_OFF);

    conv_sq_kernel<<<N_NODES, 64, 0, stream>>>(x, xhi, sq);
    wtrans_kernel<<<dim3(CDIM / 64, ODIM / 64), 256, 0, stream>>>(W1, w1t, CDIM, ODIM);
    wtrans_kernel<<<dim3(ODIM / 64, ODIM / 64), 256, 0, stream>>>(W2, w2t, ODIM, ODIM);

    gram_screen<<<GRID_G, 256, 0, stream>>>(xhi, sq, candv, candi);
    merge_topk16_kernel<<<N_NODES / 4, 256, 0, stream>>>(candv, candi, cand16, val16);
    refine_kernel<<<N_NODES / 4, 256, 0, stream>>>(x, sq, cand16, val16, knn);

    graph_init_kernel<<<(N_NODES + 255) / 256, 256, 0, stream>>>(deg, cnt);
    deg_count_kernel<<<(N_NODES * 8) / 256, 256, 0, stream>>>(knn, deg);
    dinv_kernel<<<(N_NODES + 255) / 256, 256, 0, stream>>>(deg, dinv);
    scan_kernel<<<1, 256, 0, stream>>>(deg, row_ptr);
    scatter_kernel<<<(N_NODES + 255) / 256, 256, 0, stream>>>(knn, row_ptr, cnt, col);

    hgemm_nt_kernel<<<(N_NODES / 128) * (ODIM / 128), 256, 0, stream>>>(xhi, w1t, hw, N_NODES, ODIM, CDIM);
    aggregate_kernel<true><<<N_NODES / 4, 256, 0, stream>>>(hw, row_ptr, col, dinv, b1, (void*)h1h);
    hgemm_nt_kernel<<<(N_NODES / 128) * (ODIM / 128), 256, 0, stream>>>(h1h, w2t, hw, N_NODES, ODIM, ODIM);
    aggregate_kernel<false><<<N_NODES / 4, 256, 0, stream>>>(hw, row_ptr, col, dinv, b2, (void*)out);
}

// Round 14
// 1180.923 us; speedup vs baseline: 1.4828x; 1.0140x over previous
//
#include <hip/hip_runtime.h>

typedef __attribute__((ext_vector_type(8))) _Float16 half8;
typedef __attribute__((ext_vector_type(4))) _Float16 half4;
typedef __attribute__((ext_vector_type(4))) float f32x4;

#define N_NODES 6272
#define CDIM    2048
#define ODIM    512
#define NPAN    49       // 6272 / 128 node panels
#define NSLOT   392      // 49 panels * 8 candidates per node
#define GRID_G  1232     // 8 x 154 (1225 live triangle tiles + 7 dead)
#define GATE    0.6f     // refine if approx gap(8th,9th) < GATE (err sigma ~0.03)

// ---------------- workspace layout (bytes) ----------------
#define XHI_OFF    0ul                 // 25,690,112
#define CANDV_OFF  25690112ul          // 6272*392*4 = 9,834,496
#define CANDI_OFF  35524608ul          // 6272*392*2 = 4,917,248
#define SQ_OFF     40441856ul
#define KNN_OFF    40466944ul
#define DEG_OFF    41470464ul
#define DINV_OFF   41520640ul
#define RPTR_OFF   41545728ul
#define COL_OFF    41571072ul
#define W1T_OFF    41796864ul
#define W2T_OFF    43894016ul          // -> 44,418,304
// hw (f32 12.8MB) reuses CANDV+CANDI (dead after knn_select); h1h after W2T
#define HW_OFF     CANDV_OFF
#define H1H_OFF    44418304ul

// ---------------- async global->LDS (16B per lane, wave-uniform LDS base) ----
__device__ __forceinline__ void gld_lds16(const void* g, void* l) {
    __builtin_amdgcn_global_load_lds(
        (const __attribute__((address_space(1))) void*)g,
        (__attribute__((address_space(3))) void*)l, 16, 0, 0);
}

// BK=64 tile: [row][128B]; 16B slot b holds logical k-block b ^ (row&7).
__device__ __forceinline__ half8 frag_read(const char* base, int row, int s, int lane) {
    int b = (s * 4 + (lane >> 4)) ^ (row & 7);
    return *(const half8*)(base + row * 128 + b * 16);
}

#define MF(a, b, c) __builtin_amdgcn_mfma_f32_16x16x32_f16(a, b, c, 0, 0, 0)

// ------- prep: fused x->(xhi,sq) + W1^T + W2^T (independent tiles, one launch) -------
__global__ __launch_bounds__(256) void prep_kernel(const float* __restrict__ x,
        _Float16* __restrict__ xhi, float* __restrict__ sq,
        const float* __restrict__ W1, _Float16* __restrict__ w1t,
        const float* __restrict__ W2, _Float16* __restrict__ w2t) {
    __shared__ float tile[64][65];
    int bid = blockIdx.x, tid = threadIdx.x;
    if (bid < 1568) {
        // conv_sq: 4 rows per block, one per wave
        int i = bid * 4 + (tid >> 6);
        int t = tid & 63;
        const float* row = x + (size_t)i * CDIM;
        _Float16* hrow = xhi + (size_t)i * CDIM;
        float s = 0.f;
#pragma unroll
        for (int k = 0; k < 8; k++) {
            float4 v = *(const float4*)(row + (k * 64 + t) * 4);
            half4 h;
            h[0] = (_Float16)v.x; h[1] = (_Float16)v.y;
            h[2] = (_Float16)v.z; h[3] = (_Float16)v.w;
            *(half4*)(hrow + (k * 64 + t) * 4) = h;
            s += v.x * v.x + v.y * v.y + v.z * v.z + v.w * v.w;
        }
#pragma unroll
        for (int off = 32; off; off >>= 1) s += __shfl_down(s, off, 64);
        if (t == 0) sq[i] = s;
        return;
    }
    // weight transpose tiles
    const float* W; _Float16* Wt; int K, N, idx;
    if (bid < 1824) { idx = bid - 1568; W = W1; Wt = w1t; K = CDIM; N = ODIM; }
    else            { idx = bid - 1824; W = W2; Wt = w2t; K = ODIM; N = ODIM; }
    int nkb = K / 64;
    int kb = (idx % nkb) * 64, nb = (idx / nkb) * 64;
    int r = tid >> 2, c0 = (tid & 3) * 16;
#pragma unroll
    for (int u = 0; u < 4; u++) {
        float4 v = *(const float4*)(W + (size_t)(kb + r) * N + nb + c0 + u * 4);
        tile[r][c0 + u * 4 + 0] = v.x; tile[r][c0 + u * 4 + 1] = v.y;
        tile[r][c0 + u * 4 + 2] = v.z; tile[r][c0 + u * 4 + 3] = v.w;
    }
    __syncthreads();
    int rn = tid >> 2, ck0 = (tid & 3) * 16;
#pragma unroll
    for (int u = 0; u < 4; u++) {
        half4 o;
#pragma unroll
        for (int j = 0; j < 4; j++) o[j] = (_Float16)tile[ck0 + u * 4 + j][rn];
        *(half4*)(Wt + (size_t)(nb + rn) * K + kb + ck0 + u * 4) = o;
    }
}

// ---- hi-only MFMA Gram SCREEN: upper-tri 128x128 tiles, 4+ blocks/CU ----
// TWO-STREAM staging (r11-rate hypothesis): chunk c covers k in [32c,32c+32) and
// [1024+32c, 1024+32c+32); each row's 128B LDS line = 64B from each K-half ->
// doubles the address-stream parallelism feeding L3, all else identical to r13.
__global__ __launch_bounds__(256, 4) void gram_screen(
        const _Float16* __restrict__ xhi, const float* __restrict__ sq,
        float* __restrict__ candv, unsigned short* __restrict__ candi) {
    __shared__ char lds[32768];
    float* S = (float*)lds;                                  // [128][33] 16.9KB
    float* topv = (float*)(lds + 16896);                     // [128][9]  4.6KB
    unsigned short* topi = (unsigned short*)(lds + 21504);   // [128][10] 2.6KB
#define TOPV(r, k) topv[(r) * 9 + (k)]
#define TOPI(r, k) topi[(r) * 10 + (k)]

    int tid = threadIdx.x, lane = tid & 63, wave = tid >> 6;   // 4 waves
    int wr = wave >> 1, wc = wave & 1;
    int l15 = lane & 15, kg = lane >> 4;

    // bijective XCD chunking over t-major triangle raster (1225 = 8*153 + 1)
    int xcd = blockIdx.x & 7, loc = blockIdx.x >> 3;
    if (xcd != 0 && loc >= 153) return;                        // dead pads
    int raster = (xcd == 0) ? loc : (154 + (xcd - 1) * 153 + loc);
    int t = (int)((sqrtf(8.f * (float)raster + 1.f) - 1.f) * 0.5f);
    while ((t + 1) * (t + 2) / 2 <= raster) t++;
    while (t * (t + 1) / 2 > raster) t--;
    int p = raster - t * (t + 1) / 2;                          // p <= t
    size_t i0 = (size_t)p * 128, j0 = (size_t)t * 128;

    f32x4 acc[4][4] = {};

    int r_in = lane >> 3;                  // 0..7
    int kb = (lane & 7) ^ r_in;            // pre-swizzled logical slot 0..7
    int kadd = (kb < 4) ? kb * 8 : 1024 + (kb - 4) * 8;   // two-stream K pairing

#pragma unroll 1
    for (int c = 0; c < 32; c++) {
        int kk = c * 32;
#pragma unroll
        for (int g = 0; g < 8; g++) {      // 32 segs (8 rows x 128B), 8 per wave
            int sg = wave * 8 + g;
            int tI = sg >> 4, seg = sg & 15;
            size_t row = (tI ? j0 : i0) + (size_t)(seg * 8 + r_in);
            gld_lds16(xhi + row * CDIM + kk + kadd, lds + tI * 16384 + seg * 1024);
        }
        __syncthreads();
#pragma unroll
        for (int s = 0; s < 2; s++) {
            half8 a4[4];
#pragma unroll
            for (int m = 0; m < 4; m++)
                a4[m] = frag_read(lds, wr * 64 + m * 16 + l15, s, lane);
#pragma unroll
            for (int n = 0; n < 4; n++) {
                half8 b = frag_read(lds + 16384, wc * 64 + n * 16 + l15, s, lane);
#pragma unroll
                for (int m = 0; m < 4; m++) acc[m][n] = MF(a4[m], b, acc[m][n]);
            }
        }
        __syncthreads();
    }

    float sqi[4][4];
#pragma unroll
    for (int m = 0; m < 4; m++)
#pragma unroll
        for (int r = 0; r < 4; r++)
            sqi[m][r] = sq[(int)i0 + wr * 64 + m * 16 + kg * 4 + r];
    float sqj[4];
#pragma unroll
    for (int n = 0; n < 4; n++)
        sqj[n] = sq[(int)j0 + wc * 64 + n * 16 + l15];

    if (tid < 128) {
#pragma unroll
        for (int k = 0; k < 8; k++) { TOPV(tid, k) = 3.4e38f; TOPI(tid, k) = 0xFFFF; }
    }

    // ---- row pass: 4 chunks of 32 cols ----
#pragma unroll
    for (int cs = 0; cs < 4; cs++) {
        __syncthreads();
        if (wc == (cs >> 1)) {
            const int n0 = (cs & 1) * 2;
#pragma unroll
            for (int m = 0; m < 4; m++)
#pragma unroll
                for (int nn = 0; nn < 2; nn++)
#pragma unroll
                    for (int r = 0; r < 4; r++) {
                        int row = wr * 64 + m * 16 + kg * 4 + r;
                        float d2 = sqi[m][r] + sqj[n0 + nn] - 2.f * acc[m][n0 + nn][r];
                        S[row * 33 + nn * 16 + l15] = d2;
                    }
        }
        __syncthreads();
        if (tid < 128) {
            int r = tid, gi = (int)i0 + r;
            int cbase = (int)j0 + cs * 32;
#pragma unroll 4
            for (int jj = 0; jj < 32; jj++) {
                int gj = cbase + jj;
                if (gj == gi) continue;
                float v = S[r * 33 + jj];
                float wv = TOPV(r, 7); int wi = TOPI(r, 7);
                if (v < wv || (v == wv && gj < wi)) {
                    int pos = 7;
                    while (pos > 0) {
                        float pv = TOPV(r, pos - 1); int pi = TOPI(r, pos - 1);
                        if (v < pv || (v == pv && gj < pi)) {
                            TOPV(r, pos) = pv; TOPI(r, pos) = (unsigned short)pi; pos--;
                        } else break;
                    }
                    TOPV(r, pos) = v; TOPI(r, pos) = (unsigned short)gj;
                }
            }
        }
    }
    __syncthreads();
    if (tid < 128) {
        int gi = (int)i0 + tid;
#pragma unroll
        for (int k = 0; k < 8; k++) {
            candv[(size_t)gi * NSLOT + t * 8 + k] = TOPV(tid, k);
            candi[(size_t)gi * NSLOT + t * 8 + k] = TOPI(tid, k);
        }
#pragma unroll
        for (int k = 0; k < 8; k++) { TOPV(tid, k) = 3.4e38f; TOPI(tid, k) = 0xFFFF; }
    }

    // ---- column pass (off-diagonal only): 4 chunks of 32 rows ----
    if (p < t) {
#pragma unroll
        for (int ss = 0; ss < 4; ss++) {
            __syncthreads();
            if (wr == (ss >> 1)) {
                const int mb = (ss & 1) * 2;
#pragma unroll
                for (int mm = 0; mm < 2; mm++)
#pragma unroll
                    for (int n = 0; n < 4; n++)
#pragma unroll
                        for (int r = 0; r < 4; r++) {
                            int rl  = mm * 16 + kg * 4 + r;
                            int col = wc * 64 + n * 16 + l15;
                            float d2 = sqi[mb + mm][r] + sqj[n] - 2.f * acc[mb + mm][n][r];
                            S[col * 33 + rl] = d2;
                        }
            }
            __syncthreads();
            if (tid < 128) {
                int cc = tid;
                int rbase = (int)i0 + ss * 32;
#pragma unroll 4
                for (int jj = 0; jj < 32; jj++) {
                    int gi = rbase + jj;
                    float v = S[cc * 33 + jj];
                    float wv = TOPV(cc, 7); int wi = TOPI(cc, 7);
                    if (v < wv || (v == wv && gi < wi)) {
                        int pos = 7;
                        while (pos > 0) {
                            float pv = TOPV(cc, pos - 1); int pi = TOPI(cc, pos - 1);
                            if (v < pv || (v == pv && gi < pi)) {
                                TOPV(cc, pos) = pv; TOPI(cc, pos) = (unsigned short)pi; pos--;
                            } else break;
                        }
                        TOPV(cc, pos) = v; TOPI(cc, pos) = (unsigned short)gi;
                    }
                }
            }
        }
        __syncthreads();
        if (tid < 128) {
            int gj = (int)j0 + tid;
#pragma unroll
            for (int k = 0; k < 8; k++) {
                candv[(size_t)gj * NSLOT + p * 8 + k] = TOPV(tid, k);
                candi[(size_t)gj * NSLOT + p * 8 + k] = TOPI(tid, k);
            }
        }
    }
#undef TOPV
#undef TOPI
}

// --- fused: merge 49 lists -> approx top-16 -> gated exact refine -> knn top-8 ---
__global__ __launch_bounds__(256) void knn_select_kernel(
        const float* __restrict__ candv, const unsigned short* __restrict__ candi,
        const float* __restrict__ x, const float* __restrict__ sq,
        int* __restrict__ knn) {
    int node = blockIdx.x * 4 + (threadIdx.x >> 6);
    int lane = threadIdx.x & 63;
    const float* cv = candv + (size_t)node * NSLOT;
    const unsigned short* ci = candi + (size_t)node * NSLOT;
    float v[7]; int ix[7];
#pragma unroll
    for (int u = 0; u < 7; u++) {
        int s = u * 64 + lane;
        bool ok = (s < NSLOT);
        v[u]  = ok ? cv[s] : 3.4e38f;
        ix[u] = ok ? (int)ci[s] : 0x7fffffff;
    }
    float myv16 = 3.4e38f; int myc = 0x7fffffff;   // lane k<16 owns k-th candidate
#pragma unroll 1
    for (int k = 0; k < 16; k++) {
        float bv = v[0]; int bi = ix[0];
#pragma unroll
        for (int u = 1; u < 7; u++)
            if (v[u] < bv || (v[u] == bv && ix[u] < bi)) { bv = v[u]; bi = ix[u]; }
#pragma unroll
        for (int off = 32; off; off >>= 1) {
            float ov = __shfl_xor(bv, off, 64);
            int   oi = __shfl_xor(bi, off, 64);
            if (ov < bv || (ov == bv && oi < bi)) { bv = ov; bi = oi; }
        }
        if (lane == k) { myv16 = bv; myc = bi; }
#pragma unroll
        for (int u = 0; u < 7; u++)
            if (ix[u] == bi) { v[u] = 3.4e38f; ix[u] = 0x7fffffff; }
    }
    float g7 = __shfl(myv16, 7, 64), g8 = __shfl(myv16, 8, 64);
    if (g8 - g7 > GATE) {
        if (lane < 8) knn[(size_t)node * 8 + lane] = myc;
        return;
    }
    // exact fp32 refine over the 16 candidates
    const float* xi = x + (size_t)node * CDIM;
    float4 a[8];
#pragma unroll
    for (int g = 0; g < 8; g++) a[g] = *(const float4*)(xi + (g * 64 + lane) * 4);
    float sqi = sq[node];
    float rv = 3.4e38f; int ri = 0x7fffffff;
#pragma unroll 1
    for (int c = 0; c < 16; c++) {
        int j = __shfl(myc, c, 64);
        const float* xj = x + (size_t)j * CDIM;
        float s = 0.f;
#pragma unroll
        for (int g = 0; g < 8; g++) {
            float4 b = *(const float4*)(xj + (g * 64 + lane) * 4);
            s = fmaf(a[g].x, b.x, s); s = fmaf(a[g].y, b.y, s);
            s = fmaf(a[g].z, b.z, s); s = fmaf(a[g].w, b.w, s);
        }
#pragma unroll
        for (int off = 32; off; off >>= 1) s += __shfl_down(s, off, 64);
        float d2 = sqi + sq[j] - 2.f * s;
        d2 = __shfl(d2, 0, 64);
        if (lane == c) { rv = d2; ri = j; }
    }
#pragma unroll 1
    for (int k = 0; k < 8; k++) {
        float bv = rv; int bi = ri;
#pragma unroll
        for (int off = 8; off; off >>= 1) {
            float ov = __shfl_xor(bv, off, 64);
            int   oi = __shfl_xor(bi, off, 64);
            if (ov < bv || (ov == bv && oi < bi)) { bv = ov; bi = oi; }
        }
        bv = __shfl(bv, lane & 15, 64); bi = __shfl(bi, lane & 15, 64);
        if (lane == 0) knn[(size_t)node * 8 + k] = bi;
        if (ri == bi) { rv = 3.4e38f; ri = 0x7fffffff; }
    }
}

// ---- graph build, single block: deg/cnt/rptr in LDS, one launch -----
__global__ __launch_bounds__(1024) void graph_build_kernel(
        const int* __restrict__ knn, float* __restrict__ dinv,
        int* __restrict__ row_ptr, int* __restrict__ col) {
    __shared__ int deg_l[N_NODES];
    __shared__ int cnt_l[N_NODES];
    __shared__ int rp_l[N_NODES];
    __shared__ int partial[1024];
    int tid = threadIdx.x;
    for (int i = tid; i < N_NODES; i += 1024) { deg_l[i] = 1; cnt_l[i] = 0; }
    __syncthreads();
    for (int e = tid; e < N_NODES * 8; e += 1024) atomicAdd(&deg_l[knn[e]], 1);
    __syncthreads();
    const int CH = 7;                       // ceil(6272/1024)
    int start = tid * CH;
    int end = start + CH; if (end > N_NODES) end = N_NODES;
    int s = 0;
    for (int i = start; i < end; i++) s += deg_l[i];
    partial[tid] = s;
    __syncthreads();
    if (tid == 0) {
        int run = 0;
        for (int k = 0; k < 1024; k++) { int vv = partial[k]; partial[k] = run; run += vv; }
        row_ptr[N_NODES] = run;
    }
    __syncthreads();
    int run = partial[tid];
    for (int i = start; i < end; i++) {
        rp_l[i] = run; row_ptr[i] = run;
        dinv[i] = rsqrtf((float)deg_l[i]);
        run += deg_l[i];
    }
    __syncthreads();
    for (int i = tid; i < N_NODES; i += 1024) {
        int p0 = rp_l[i] + atomicAdd(&cnt_l[i], 1);
        col[p0] = i;                        // self-loop
#pragma unroll
        for (int j = 0; j < 8; j++) {
            int d = knn[i * 8 + j];
            int q = rp_l[d] + atomicAdd(&cnt_l[d], 1);
            col[q] = i;
        }
    }
}

// ------------- fp16 MFMA GEMM  C[M,N] = A[M,K] @ Bt[N,K]^T  (f32 out) --------
__global__ __launch_bounds__(256) void hgemm_nt_kernel(
        const _Float16* __restrict__ A, const _Float16* __restrict__ Bt,
        float* __restrict__ C, int M, int N, int K) {
    __shared__ char Alds[16384], Blds[16384];
    int tid = threadIdx.x, lane = tid & 63, wave = tid >> 6;
    int wr = wave >> 1, wc = wave & 1;
    int l15 = lane & 15, kg = lane >> 4;
    int nt = N >> 7;
    int i0 = (blockIdx.x / nt) * 128, j0 = (blockIdx.x % nt) * 128;
    f32x4 acc[4][4] = {};

#pragma unroll 1
    for (int kk = 0; kk < K; kk += 64) {
        __syncthreads();
#pragma unroll
        for (int g = 0; g < 4; g++) {
            int R = wave * 32 + g * 8;
            int swzk = ((lane & 7) ^ (lane >> 3)) << 3;
            const _Float16* ga = A + (size_t)(i0 + R + (lane >> 3)) * K + kk + swzk;
            gld_lds16(ga, Alds + R * 128);
            const _Float16* gb = Bt + (size_t)(j0 + R + (lane >> 3)) * K + kk + swzk;
            gld_lds16(gb, Blds + R * 128);
        }
        __syncthreads();
#pragma unroll
        for (int s = 0; s < 2; s++) {
            half8 a[4], b[4];
#pragma unroll
            for (int m = 0; m < 4; m++) a[m] = frag_read(Alds, wr * 64 + m * 16 + l15, s, lane);
#pragma unroll
            for (int n = 0; n < 4; n++) b[n] = frag_read(Blds, wc * 64 + n * 16 + l15, s, lane);
#pragma unroll
            for (int m = 0; m < 4; m++)
#pragma unroll
                for (int n = 0; n < 4; n++)
                    acc[m][n] = __builtin_amdgcn_mfma_f32_16x16x32_f16(a[m], b[n], acc[m][n], 0, 0, 0);
        }
    }
#pragma unroll
    for (int m = 0; m < 4; m++)
#pragma unroll
        for (int n = 0; n < 4; n++)
#pragma unroll
            for (int r = 0; r < 4; r++) {
                int row = i0 + wr * 64 + m * 16 + kg * 4 + r;
                int colj = j0 + wc * 64 + n * 16 + l15;
                C[(size_t)row * N + colj] = acc[m][n][r];
            }
}

// ------------- GCN aggregation: out[d] = relu(dinv[d]*sum hw[s]*dinv[s] + b) ---
template <bool HALF>
__global__ __launch_bounds__(256) void aggregate_kernel(
        const float* __restrict__ hw, const int* __restrict__ row_ptr,
        const int* __restrict__ col, const float* __restrict__ dinv,
        const float* __restrict__ bias, void* __restrict__ outp) {
    int node = blockIdx.x * 4 + (threadIdx.x >> 6);
    int lane = threadIdx.x & 63;
    int e0 = row_ptr[node], e1 = row_ptr[node + 1];
    float4 acc0 = {0.f, 0.f, 0.f, 0.f}, acc1 = {0.f, 0.f, 0.f, 0.f};
    for (int e = e0; e < e1; e++) {
        int s = col[e];
        float w = dinv[s];
        const float* hr = hw + (size_t)s * ODIM;
        float4 v0 = *(const float4*)(hr + lane * 4);
        float4 v1 = *(const float4*)(hr + 256 + lane * 4);
        acc0.x = fmaf(w, v0.x, acc0.x); acc0.y = fmaf(w, v0.y, acc0.y);
        acc0.z = fmaf(w, v0.z, acc0.z); acc0.w = fmaf(w, v0.w, acc0.w);
        acc1.x = fmaf(w, v1.x, acc1.x); acc1.y = fmaf(w, v1.y, acc1.y);
        acc1.z = fmaf(w, v1.z, acc1.z); acc1.w = fmaf(w, v1.w, acc1.w);
    }
    float wd = dinv[node];
    float4 b0 = *(const float4*)(bias + lane * 4);
    float4 b1 = *(const float4*)(bias + 256 + lane * 4);
    float o[8];
    o[0] = fmaxf(fmaf(acc0.x, wd, b0.x), 0.f);
    o[1] = fmaxf(fmaf(acc0.y, wd, b0.y), 0.f);
    o[2] = fmaxf(fmaf(acc0.z, wd, b0.z), 0.f);
    o[3] = fmaxf(fmaf(acc0.w, wd, b0.w), 0.f);
    o[4] = fmaxf(fmaf(acc1.x, wd, b1.x), 0.f);
    o[5] = fmaxf(fmaf(acc1.y, wd, b1.y), 0.f);
    o[6] = fmaxf(fmaf(acc1.z, wd, b1.z), 0.f);
    o[7] = fmaxf(fmaf(acc1.w, wd, b1.w), 0.f);
    if (HALF) {
        _Float16* out = (_Float16*)outp;
        half4 h0, h1;
#pragma unroll
        for (int j = 0; j < 4; j++) { h0[j] = (_Float16)o[j]; h1[j] = (_Float16)o[4 + j]; }
        *(half4*)(out + (size_t)node * ODIM + lane * 4)       = h0;
        *(half4*)(out + (size_t)node * ODIM + 256 + lane * 4) = h1;
    } else {
        float* out = (float*)outp;
        float4 f0 = {o[0], o[1], o[2], o[3]}, f1 = {o[4], o[5], o[6], o[7]};
        *(float4*)(out + (size_t)node * ODIM + lane * 4)       = f0;
        *(float4*)(out + (size_t)node * ODIM + 256 + lane * 4) = f1;
    }
}

extern "C" void kernel_launch(void* const* d_in, const int* in_sizes, int n_in,
                              void* d_out, int out_size, void* d_ws, size_t ws_size,
                              hipStream_t stream) {
    const float* x  = (const float*)d_in[0];
    const float* W1 = (const float*)d_in[1];
    const float* b1 = (const float*)d_in[2];
    const float* W2 = (const float*)d_in[3];
    const float* b2 = (const float*)d_in[4];
    float* out = (float*)d_out;
    char* ws = (char*)d_ws;

    _Float16* xhi  = (_Float16*)(ws + XHI_OFF);
    float* candv   = (float*)(ws + CANDV_OFF);
    unsigned short* candi = (unsigned short*)(ws + CANDI_OFF);
    float* sq      = (float*)(ws + SQ_OFF);
    int*   knn     = (int*)  (ws + KNN_OFF);
    float* dinv    = (float*)(ws + DINV_OFF);
    int*   row_ptr = (int*)  (ws + RPTR_OFF);
    int*   col     = (int*)  (ws + COL_OFF);
    _Float16* w1t  = (_Float16*)(ws + W1T_OFF);
    _Float16* w2t  = (_Float16*)(ws + W2T_OFF);
    float* hw      = (float*)(ws + HW_OFF);       // reuses candv/candi
    _Float16* h1h  = (_Float16*)(ws + H1H_OFF);

    prep_kernel<<<1888, 256, 0, stream>>>(x, xhi, sq, W1, w1t, W2, w2t);
    gram_screen<<<GRID_G, 256, 0, stream>>>(xhi, sq, candv, candi);
    knn_select_kernel<<<N_NODES / 4, 256, 0, stream>>>(candv, candi, x, sq, knn);
    graph_build_kernel<<<1, 1024, 0, stream>>>(knn, dinv, row_ptr, col);

    hgemm_nt_kernel<<<(N_NODES / 128) * (ODIM / 128), 256, 0, stream>>>(xhi, w1t, hw, N_NODES, ODIM, CDIM);
    aggregate_kernel<true><<<N_NODES / 4, 256, 0, stream>>>(hw, row_ptr, col, dinv, b1, (void*)h1h);
    hgemm_nt_kernel<<<(N_NODES / 128) * (ODIM / 128), 256, 0, stream>>>(h1h, w2t, hw, N_NODES, ODIM, ODIM);
    aggregate_kernel<false><<<N_NODES / 4, 256, 0, stream>>>(hw, row_ptr, col, dinv, b2, (void*)out);
}

// Round 15
// 1131.368 us; speedup vs baseline: 1.5477x; 1.0438x over previous
//
#include <hip/hip_runtime.h>

typedef __attribute__((ext_vector_type(8))) _Float16 half8;
typedef __attribute__((ext_vector_type(4))) _Float16 half4;
typedef __attribute__((ext_vector_type(4))) float f32x4;

#define N_NODES 6272
#define CDIM    2048
#define ODIM    512
#define NPAN    49       // 6272 / 128 node panels
#define NSLOT   392      // 49 panels * 8 candidates per node
#define GRID_G  1232     // 8 x 154 (1225 live triangle tiles + 7 dead)
#define GATE    0.6f     // refine if approx gap(8th,9th) < GATE (err sigma ~0.03)

// ---------------- workspace layout (bytes) ----------------
#define XHI_OFF    0ul                 // 25,690,112
#define CANDV_OFF  25690112ul          // 6272*392*4 = 9,834,496
#define CANDI_OFF  35524608ul          // 6272*392*2 = 4,917,248
#define SQ_OFF     40441856ul
#define KNN_OFF    40466944ul
#define DINV_OFF   41520640ul
#define RPTR_OFF   41545728ul
#define COL_OFF    41571072ul
#define W1T_OFF    41796864ul
#define W2T_OFF    43894016ul          // -> 44,418,304
// hw (f16 6.4MB) reuses CANDV (dead after knn_select); h1h after W2T
#define HW_OFF     CANDV_OFF
#define H1H_OFF    44418304ul

// ---------------- async global->LDS (16B per lane, wave-uniform LDS base) ----
__device__ __forceinline__ void gld_lds16(const void* g, void* l) {
    __builtin_amdgcn_global_load_lds(
        (const __attribute__((address_space(1))) void*)g,
        (__attribute__((address_space(3))) void*)l, 16, 0, 0);
}

// BK=64 tile: [row][128B]; 16B slot b holds logical k-block b ^ (row&7).
__device__ __forceinline__ half8 frag_read(const char* base, int row, int s, int lane) {
    int b = (s * 4 + (lane >> 4)) ^ (row & 7);
    return *(const half8*)(base + row * 128 + b * 16);
}

#define MF(a, b, c) __builtin_amdgcn_mfma_f32_16x16x32_f16(a, b, c, 0, 0, 0)

// ------- prep: fused x->(xhi,sq) + W1^T + W2^T (independent tiles, one launch) -------
__global__ __launch_bounds__(256) void prep_kernel(const float* __restrict__ x,
        _Float16* __restrict__ xhi, float* __restrict__ sq,
        const float* __restrict__ W1, _Float16* __restrict__ w1t,
        const float* __restrict__ W2, _Float16* __restrict__ w2t) {
    __shared__ float tile[64][65];
    int bid = blockIdx.x, tid = threadIdx.x;
    if (bid < 1568) {
        int i = bid * 4 + (tid >> 6);
        int t = tid & 63;
        const float* row = x + (size_t)i * CDIM;
        _Float16* hrow = xhi + (size_t)i * CDIM;
        float s = 0.f;
#pragma unroll
        for (int k = 0; k < 8; k++) {
            float4 v = *(const float4*)(row + (k * 64 + t) * 4);
            half4 h;
            h[0] = (_Float16)v.x; h[1] = (_Float16)v.y;
            h[2] = (_Float16)v.z; h[3] = (_Float16)v.w;
            *(half4*)(hrow + (k * 64 + t) * 4) = h;
            s += v.x * v.x + v.y * v.y + v.z * v.z + v.w * v.w;
        }
#pragma unroll
        for (int off = 32; off; off >>= 1) s += __shfl_down(s, off, 64);
        if (t == 0) sq[i] = s;
        return;
    }
    const float* W; _Float16* Wt; int K, N, idx;
    if (bid < 1824) { idx = bid - 1568; W = W1; Wt = w1t; K = CDIM; N = ODIM; }
    else            { idx = bid - 1824; W = W2; Wt = w2t; K = ODIM; N = ODIM; }
    int nkb = K / 64;
    int kb = (idx % nkb) * 64, nb = (idx / nkb) * 64;
    int r = tid >> 2, c0 = (tid & 3) * 16;
#pragma unroll
    for (int u = 0; u < 4; u++) {
        float4 v = *(const float4*)(W + (size_t)(kb + r) * N + nb + c0 + u * 4);
        tile[r][c0 + u * 4 + 0] = v.x; tile[r][c0 + u * 4 + 1] = v.y;
        tile[r][c0 + u * 4 + 2] = v.z; tile[r][c0 + u * 4 + 3] = v.w;
    }
    __syncthreads();
    int rn = tid >> 2, ck0 = (tid & 3) * 16;
#pragma unroll
    for (int u = 0; u < 4; u++) {
        half4 o;
#pragma unroll
        for (int j = 0; j < 4; j++) o[j] = (_Float16)tile[ck0 + u * 4 + j][rn];
        *(half4*)(Wt + (size_t)(nb + rn) * K + kb + ck0 + u * 4) = o;
    }
}

// ---- hi-only MFMA Gram SCREEN (r13 staging: contiguous 128B/row lines) ----
__global__ __launch_bounds__(256, 4) void gram_screen(
        const _Float16* __restrict__ xhi, const float* __restrict__ sq,
        float* __restrict__ candv, unsigned short* __restrict__ candi) {
    __shared__ char lds[32768];
    float* S = (float*)lds;                                  // [128][33] 16.9KB
    float* topv = (float*)(lds + 16896);                     // [128][9]  4.6KB
    unsigned short* topi = (unsigned short*)(lds + 21504);   // [128][10] 2.6KB
#define TOPV(r, k) topv[(r) * 9 + (k)]
#define TOPI(r, k) topi[(r) * 10 + (k)]

    int tid = threadIdx.x, lane = tid & 63, wave = tid >> 6;   // 4 waves
    int wr = wave >> 1, wc = wave & 1;
    int l15 = lane & 15, kg = lane >> 4;

    // bijective XCD chunking over t-major triangle raster (1225 = 8*153 + 1)
    int xcd = blockIdx.x & 7, loc = blockIdx.x >> 3;
    if (xcd != 0 && loc >= 153) return;
    int raster = (xcd == 0) ? loc : (154 + (xcd - 1) * 153 + loc);
    int t = (int)((sqrtf(8.f * (float)raster + 1.f) - 1.f) * 0.5f);
    while ((t + 1) * (t + 2) / 2 <= raster) t++;
    while (t * (t + 1) / 2 > raster) t--;
    int p = raster - t * (t + 1) / 2;                          // p <= t
    size_t i0 = (size_t)p * 128, j0 = (size_t)t * 128;

    f32x4 acc[4][4] = {};

    int r_in = lane >> 3;
    int skb = (lane & 7) ^ r_in;           // pre-swizzled 16B block (matches frag_read)

#pragma unroll 1
    for (int c = 0; c < 32; c++) {
        int kk = c * 64;
#pragma unroll
        for (int g = 0; g < 8; g++) {      // 32 segs (8 rows x 128B), 8 per wave
            int sg = wave * 8 + g;
            int tI = sg >> 4, seg = sg & 15;
            size_t row = (tI ? j0 : i0) + (size_t)(seg * 8 + r_in);
            gld_lds16(xhi + row * CDIM + kk + skb * 8, lds + tI * 16384 + seg * 1024);
        }
        __syncthreads();
#pragma unroll
        for (int s = 0; s < 2; s++) {
            half8 a4[4];
#pragma unroll
            for (int m = 0; m < 4; m++)
                a4[m] = frag_read(lds, wr * 64 + m * 16 + l15, s, lane);
#pragma unroll
            for (int n = 0; n < 4; n++) {
                half8 b = frag_read(lds + 16384, wc * 64 + n * 16 + l15, s, lane);
#pragma unroll
                for (int m = 0; m < 4; m++) acc[m][n] = MF(a4[m], b, acc[m][n]);
            }
        }
        __syncthreads();
    }

    float sqi[4][4];
#pragma unroll
    for (int m = 0; m < 4; m++)
#pragma unroll
        for (int r = 0; r < 4; r++)
            sqi[m][r] = sq[(int)i0 + wr * 64 + m * 16 + kg * 4 + r];
    float sqj[4];
#pragma unroll
    for (int n = 0; n < 4; n++)
        sqj[n] = sq[(int)j0 + wc * 64 + n * 16 + l15];

    if (tid < 128) {
#pragma unroll
        for (int k = 0; k < 8; k++) { TOPV(tid, k) = 3.4e38f; TOPI(tid, k) = 0xFFFF; }
    }

    // ---- row pass ----
#pragma unroll
    for (int cs = 0; cs < 4; cs++) {
        __syncthreads();
        if (wc == (cs >> 1)) {
            const int n0 = (cs & 1) * 2;
#pragma unroll
            for (int m = 0; m < 4; m++)
#pragma unroll
                for (int nn = 0; nn < 2; nn++)
#pragma unroll
                    for (int r = 0; r < 4; r++) {
                        int row = wr * 64 + m * 16 + kg * 4 + r;
                        float d2 = sqi[m][r] + sqj[n0 + nn] - 2.f * acc[m][n0 + nn][r];
                        S[row * 33 + nn * 16 + l15] = d2;
                    }
        }
        __syncthreads();
        if (tid < 128) {
            int r = tid, gi = (int)i0 + r;
            int cbase = (int)j0 + cs * 32;
#pragma unroll 4
            for (int jj = 0; jj < 32; jj++) {
                int gj = cbase + jj;
                if (gj == gi) continue;
                float v = S[r * 33 + jj];
                float wv = TOPV(r, 7); int wi = TOPI(r, 7);
                if (v < wv || (v == wv && gj < wi)) {
                    int pos = 7;
                    while (pos > 0) {
                        float pv = TOPV(r, pos - 1); int pi = TOPI(r, pos - 1);
                        if (v < pv || (v == pv && gj < pi)) {
                            TOPV(r, pos) = pv; TOPI(r, pos) = (unsigned short)pi; pos--;
                        } else break;
                    }
                    TOPV(r, pos) = v; TOPI(r, pos) = (unsigned short)gj;
                }
            }
        }
    }
    __syncthreads();
    if (tid < 128) {
        int gi = (int)i0 + tid;
#pragma unroll
        for (int k = 0; k < 8; k++) {
            candv[(size_t)gi * NSLOT + t * 8 + k] = TOPV(tid, k);
            candi[(size_t)gi * NSLOT + t * 8 + k] = TOPI(tid, k);
        }
#pragma unroll
        for (int k = 0; k < 8; k++) { TOPV(tid, k) = 3.4e38f; TOPI(tid, k) = 0xFFFF; }
    }

    // ---- column pass (off-diagonal only) ----
    if (p < t) {
#pragma unroll
        for (int ss = 0; ss < 4; ss++) {
            __syncthreads();
            if (wr == (ss >> 1)) {
                const int mb = (ss & 1) * 2;
#pragma unroll
                for (int mm = 0; mm < 2; mm++)
#pragma unroll
                    for (int n = 0; n < 4; n++)
#pragma unroll
                        for (int r = 0; r < 4; r++) {
                            int rl  = mm * 16 + kg * 4 + r;
                            int col = wc * 64 + n * 16 + l15;
                            float d2 = sqi[mb + mm][r] + sqj[n] - 2.f * acc[mb + mm][n][r];
                            S[col * 33 + rl] = d2;
                        }
            }
            __syncthreads();
            if (tid < 128) {
                int cc = tid;
                int rbase = (int)i0 + ss * 32;
#pragma unroll 4
                for (int jj = 0; jj < 32; jj++) {
                    int gi = rbase + jj;
                    float v = S[cc * 33 + jj];
                    float wv = TOPV(cc, 7); int wi = TOPI(cc, 7);
                    if (v < wv || (v == wv && gi < wi)) {
                        int pos = 7;
                        while (pos > 0) {
                            float pv = TOPV(cc, pos - 1); int pi = TOPI(cc, pos - 1);
                            if (v < pv || (v == pv && gi < pi)) {
                                TOPV(cc, pos) = pv; TOPI(cc, pos) = (unsigned short)pi; pos--;
                            } else break;
                        }
                        TOPV(cc, pos) = v; TOPI(cc, pos) = (unsigned short)gi;
                    }
                }
            }
        }
        __syncthreads();
        if (tid < 128) {
            int gj = (int)j0 + tid;
#pragma unroll
            for (int k = 0; k < 8; k++) {
                candv[(size_t)gj * NSLOT + p * 8 + k] = TOPV(tid, k);
                candi[(size_t)gj * NSLOT + p * 8 + k] = TOPI(tid, k);
            }
        }
    }
#undef TOPV
#undef TOPI
}

// --- fused: merge 49 lists -> approx top-16 -> gated exact refine -> knn top-8 ---
__global__ __launch_bounds__(256) void knn_select_kernel(
        const float* __restrict__ candv, const unsigned short* __restrict__ candi,
        const float* __restrict__ x, const float* __restrict__ sq,
        int* __restrict__ knn) {
    int node = blockIdx.x * 4 + (threadIdx.x >> 6);
    int lane = threadIdx.x & 63;
    const float* cv = candv + (size_t)node * NSLOT;
    const unsigned short* ci = candi + (size_t)node * NSLOT;
    float v[7]; int ix[7];
#pragma unroll
    for (int u = 0; u < 7; u++) {
        int s = u * 64 + lane;
        bool ok = (s < NSLOT);
        v[u]  = ok ? cv[s] : 3.4e38f;
        ix[u] = ok ? (int)ci[s] : 0x7fffffff;
    }
    float myv16 = 3.4e38f; int myc = 0x7fffffff;
#pragma unroll 1
    for (int k = 0; k < 16; k++) {
        float bv = v[0]; int bi = ix[0];
#pragma unroll
        for (int u = 1; u < 7; u++)
            if (v[u] < bv || (v[u] == bv && ix[u] < bi)) { bv = v[u]; bi = ix[u]; }
#pragma unroll
        for (int off = 32; off; off >>= 1) {
            float ov = __shfl_xor(bv, off, 64);
            int   oi = __shfl_xor(bi, off, 64);
            if (ov < bv || (ov == bv && oi < bi)) { bv = ov; bi = oi; }
        }
        if (lane == k) { myv16 = bv; myc = bi; }
#pragma unroll
        for (int u = 0; u < 7; u++)
            if (ix[u] == bi) { v[u] = 3.4e38f; ix[u] = 0x7fffffff; }
    }
    float g7 = __shfl(myv16, 7, 64), g8 = __shfl(myv16, 8, 64);
    if (g8 - g7 > GATE) {
        if (lane < 8) knn[(size_t)node * 8 + lane] = myc;
        return;
    }
    const float* xi = x + (size_t)node * CDIM;
    float4 a[8];
#pragma unroll
    for (int g = 0; g < 8; g++) a[g] = *(const float4*)(xi + (g * 64 + lane) * 4);
    float sqi = sq[node];
    float rv = 3.4e38f; int ri = 0x7fffffff;
#pragma unroll 1
    for (int c = 0; c < 16; c++) {
        int j = __shfl(myc, c, 64);
        const float* xj = x + (size_t)j * CDIM;
        float s = 0.f;
#pragma unroll
        for (int g = 0; g < 8; g++) {
            float4 b = *(const float4*)(xj + (g * 64 + lane) * 4);
            s = fmaf(a[g].x, b.x, s); s = fmaf(a[g].y, b.y, s);
            s = fmaf(a[g].z, b.z, s); s = fmaf(a[g].w, b.w, s);
        }
#pragma unroll
        for (int off = 32; off; off >>= 1) s += __shfl_down(s, off, 64);
        float d2 = sqi + sq[j] - 2.f * s;
        d2 = __shfl(d2, 0, 64);
        if (lane == c) { rv = d2; ri = j; }
    }
#pragma unroll 1
    for (int k = 0; k < 8; k++) {
        float bv = rv; int bi = ri;
#pragma unroll
        for (int off = 8; off; off >>= 1) {
            float ov = __shfl_xor(bv, off, 64);
            int   oi = __shfl_xor(bi, off, 64);
            if (ov < bv || (ov == bv && oi < bi)) { bv = ov; bi = oi; }
        }
        bv = __shfl(bv, lane & 15, 64); bi = __shfl(bi, lane & 15, 64);
        if (lane == 0) knn[(size_t)node * 8 + k] = bi;
        if (ri == bi) { rv = 3.4e38f; ri = 0x7fffffff; }
    }
}

// ---- graph build, single block: deg/cnt/rptr in LDS, one launch -----
__global__ __launch_bounds__(1024) void graph_build_kernel(
        const int* __restrict__ knn, float* __restrict__ dinv,
        int* __restrict__ row_ptr, int* __restrict__ col) {
    __shared__ int deg_l[N_NODES];
    __shared__ int cnt_l[N_NODES];
    __shared__ int rp_l[N_NODES];
    __shared__ int partial[1024];
    int tid = threadIdx.x;
    for (int i = tid; i < N_NODES; i += 1024) { deg_l[i] = 1; cnt_l[i] = 0; }
    __syncthreads();
    for (int e = tid; e < N_NODES * 8; e += 1024) atomicAdd(&deg_l[knn[e]], 1);
    __syncthreads();
    const int CH = 7;
    int start = tid * CH;
    int end = start + CH; if (end > N_NODES) end = N_NODES;
    int s = 0;
    for (int i = start; i < end; i++) s += deg_l[i];
    partial[tid] = s;
    __syncthreads();
    if (tid == 0) {
        int run = 0;
        for (int k = 0; k < 1024; k++) { int vv = partial[k]; partial[k] = run; run += vv; }
        row_ptr[N_NODES] = run;
    }
    __syncthreads();
    int run = partial[tid];
    for (int i = start; i < end; i++) {
        rp_l[i] = run; row_ptr[i] = run;
        dinv[i] = rsqrtf((float)deg_l[i]);
        run += deg_l[i];
    }
    __syncthreads();
    for (int i = tid; i < N_NODES; i += 1024) {
        int p0 = rp_l[i] + atomicAdd(&cnt_l[i], 1);
        col[p0] = i;
#pragma unroll
        for (int j = 0; j < 8; j++) {
            int d = knn[i * 8 + j];
            int q = rp_l[d] + atomicAdd(&cnt_l[d], 1);
            col[q] = i;
        }
    }
}

// ---- fp16 MFMA GEMM, 64x128 tiles (392 blocks), f16 out, XCD-swizzled ----
// C[M,N] f16 = A[M,K] f16 @ Bt[N,K]^T. 256 thr / 4 waves, each wave 64x32.
__global__ __launch_bounds__(256) void hgemm_nt_kernel(
        const _Float16* __restrict__ A, const _Float16* __restrict__ Bt,
        _Float16* __restrict__ C, int M, int N, int K) {
    __shared__ char lds[24576];        // A 8KB | B 16KB
    int tid = threadIdx.x, lane = tid & 63, wave = tid >> 6;
    int l15 = lane & 15, kg = lane >> 4;
    int nt = N >> 7;
    // XCD swizzle: xcd gets 49 consecutive i-tiles of one j-column (B L2-reuse)
    int nblk = (M >> 6) * nt;
    int per = nblk >> 3;               // 49 for M=6272,N=512
    int swz = (blockIdx.x & 7) * per + (blockIdx.x >> 3);
    int i0 = (swz % (M >> 6)) * 64, j0 = (swz / (M >> 6)) * 128;
    f32x4 acc[4][2] = {};

    int r_in = lane >> 3;
    int skb = (lane & 7) ^ r_in;

#pragma unroll 1
    for (int kk = 0; kk < K; kk += 64) {
        __syncthreads();
#pragma unroll
        for (int g = 0; g < 6; g++) {      // 24 segs: A 8, B 16; 6 per wave
            int sg = wave * 6 + g;
            if (sg < 8) {
                gld_lds16(A + (size_t)(i0 + sg * 8 + r_in) * K + kk + skb * 8,
                          lds + sg * 1024);
            } else {
                int seg = sg - 8;
                gld_lds16(Bt + (size_t)(j0 + seg * 8 + r_in) * K + kk + skb * 8,
                          lds + 8192 + seg * 1024);
            }
        }
        __syncthreads();
#pragma unroll
        for (int s = 0; s < 2; s++) {
            half8 a[4];
#pragma unroll
            for (int m = 0; m < 4; m++) a[m] = frag_read(lds, m * 16 + l15, s, lane);
#pragma unroll
            for (int n = 0; n < 2; n++) {
                half8 b = frag_read(lds + 8192, wave * 32 + n * 16 + l15, s, lane);
#pragma unroll
                for (int m = 0; m < 4; m++) acc[m][n] = MF(a[m], b, acc[m][n]);
            }
        }
    }
#pragma unroll
    for (int m = 0; m < 4; m++)
#pragma unroll
        for (int n = 0; n < 2; n++)
#pragma unroll
            for (int r = 0; r < 4; r++) {
                int row = i0 + m * 16 + kg * 4 + r;
                int colj = j0 + wave * 32 + n * 16 + l15;
                C[(size_t)row * N + colj] = (_Float16)acc[m][n][r];
            }
}

// --- GCN aggregation (f16 in): out[d] = relu(dinv[d]*sum hw[s]*dinv[s] + b) ---
template <bool HALF_OUT>
__global__ __launch_bounds__(256) void aggregate_kernel(
        const _Float16* __restrict__ hw, const int* __restrict__ row_ptr,
        const int* __restrict__ col, const float* __restrict__ dinv,
        const float* __restrict__ bias, void* __restrict__ outp) {
    int node = blockIdx.x * 4 + (threadIdx.x >> 6);
    int lane = threadIdx.x & 63;
    int e0 = row_ptr[node], e1 = row_ptr[node + 1];
    float acc[8] = {};
    for (int e = e0; e < e1; e++) {
        int s = col[e];
        float w = dinv[s];
        half8 v = *(const half8*)(hw + (size_t)s * ODIM + lane * 8);
#pragma unroll
        for (int j = 0; j < 8; j++) acc[j] = fmaf(w, (float)v[j], acc[j]);
    }
    float wd = dinv[node];
    float4 b0 = *(const float4*)(bias + lane * 8);
    float4 b1 = *(const float4*)(bias + lane * 8 + 4);
    float o[8];
    o[0] = fmaxf(fmaf(acc[0], wd, b0.x), 0.f);
    o[1] = fmaxf(fmaf(acc[1], wd, b0.y), 0.f);
    o[2] = fmaxf(fmaf(acc[2], wd, b0.z), 0.f);
    o[3] = fmaxf(fmaf(acc[3], wd, b0.w), 0.f);
    o[4] = fmaxf(fmaf(acc[4], wd, b1.x), 0.f);
    o[5] = fmaxf(fmaf(acc[5], wd, b1.y), 0.f);
    o[6] = fmaxf(fmaf(acc[6], wd, b1.z), 0.f);
    o[7] = fmaxf(fmaf(acc[7], wd, b1.w), 0.f);
    if (HALF_OUT) {
        half8 h;
#pragma unroll
        for (int j = 0; j < 8; j++) h[j] = (_Float16)o[j];
        *(half8*)((_Float16*)outp + (size_t)node * ODIM + lane * 8) = h;
    } else {
        float* out = (float*)outp;
        float4 f0 = {o[0], o[1], o[2], o[3]}, f1 = {o[4], o[5], o[6], o[7]};
        *(float4*)(out + (size_t)node * ODIM + lane * 8)     = f0;
        *(float4*)(out + (size_t)node * ODIM + lane * 8 + 4) = f1;
    }
}

extern "C" void kernel_launch(void* const* d_in, const int* in_sizes, int n_in,
                              void* d_out, int out_size, void* d_ws, size_t ws_size,
                              hipStream_t stream) {
    const float* x  = (const float*)d_in[0];
    const float* W1 = (const float*)d_in[1];
    const float* b1 = (const float*)d_in[2];
    const float* W2 = (const float*)d_in[3];
    const float* b2 = (const float*)d_in[4];
    float* out = (float*)d_out;
    char* ws = (char*)d_ws;

    _Float16* xhi  = (_Float16*)(ws + XHI_OFF);
    float* candv   = (float*)(ws + CANDV_OFF);
    unsigned short* candi = (unsigned short*)(ws + CANDI_OFF);
    float* sq      = (float*)(ws + SQ_OFF);
    int*   knn     = (int*)  (ws + KNN_OFF);
    float* dinv    = (float*)(ws + DINV_OFF);
    int*   row_ptr = (int*)  (ws + RPTR_OFF);
    int*   col     = (int*)  (ws + COL_OFF);
    _Float16* w1t  = (_Float16*)(ws + W1T_OFF);
    _Float16* w2t  = (_Float16*)(ws + W2T_OFF);
    _Float16* hw   = (_Float16*)(ws + HW_OFF);    // reuses candv (post-select)
    _Float16* h1h  = (_Float16*)(ws + H1H_OFF);

    prep_kernel<<<1888, 256, 0, stream>>>(x, xhi, sq, W1, w1t, W2, w2t);
    gram_screen<<<GRID_G, 256, 0, stream>>>(xhi, sq, candv, candi);
    knn_select_kernel<<<N_NODES / 4, 256, 0, stream>>>(candv, candi, x, sq, knn);
    graph_build_kernel<<<1, 1024, 0, stream>>>(knn, dinv, row_ptr, col);

    hgemm_nt_kernel<<<(N_NODES / 64) * (ODIM / 128), 256, 0, stream>>>(xhi, w1t, hw, N_NODES, ODIM, CDIM);
    aggregate_kernel<true><<<N_NODES / 4, 256, 0, stream>>>(hw, row_ptr, col, dinv, b1, (void*)h1h);
    hgemm_nt_kernel<<<(N_NODES / 64) * (ODIM / 128), 256, 0, stream>>>(h1h, w2t, hw, N_NODES, ODIM, ODIM);
    aggregate_kernel<false><<<N_NODES / 4, 256, 0, stream>>>(hw, row_ptr, col, dinv, b2, (void*)out);
}

// Round 16
// 1100.177 us; speedup vs baseline: 1.5916x; 1.0284x over previous
//
#include <hip/hip_runtime.h>

typedef __attribute__((ext_vector_type(8))) _Float16 half8;
typedef __attribute__((ext_vector_type(4))) _Float16 half4;
typedef __attribute__((ext_vector_type(4))) float f32x4;

#define N_NODES 6272
#define CDIM    2048
#define ODIM    512
#define NPAN    49       // 6272 / 128 node panels
#define NSLOT   392      // 49 panels * 8 candidates per node
#define GRID_G  1232     // 8 x 154 (1225 live triangle tiles + 7 dead)
#define GRID_H1 392      // hgemm layer-1 blocks (64x128 tiles)
#define GATE    0.6f     // refine if approx gap(8th,9th) < GATE (err sigma ~0.05)

// ---------------- workspace layout (bytes) ----------------
#define XHI_OFF    0ul                 // 25,690,112
#define CANDV_OFF  25690112ul          // 6272*392*4 = 9,834,496
#define CANDI_OFF  35524608ul          // 6272*392*2 = 4,917,248
#define SQ_OFF     40441856ul
#define KNN_OFF    40466944ul
#define DINV_OFF   41520640ul
#define RPTR_OFF   41545728ul
#define COL_OFF    41571072ul
#define W1T_OFF    41796864ul
#define W2T_OFF    43894016ul          // -> 44,418,304
#define H1H_OFF    44418304ul          // f16 6.4MB -> 50,843,648
#define HW_OFF     50843648ul          // f16 6.4MB (own region: gram writes candv
                                       // concurrently with hgemm1 writing hw)

// ---------------- async global->LDS (16B per lane, wave-uniform LDS base) ----
__device__ __forceinline__ void gld_lds16(const void* g, void* l) {
    __builtin_amdgcn_global_load_lds(
        (const __attribute__((address_space(1))) void*)g,
        (__attribute__((address_space(3))) void*)l, 16, 0, 0);
}

// BK=64 tile: [row][128B]; 16B slot b holds logical k-block b ^ (row&7).
__device__ __forceinline__ half8 frag_read(const char* base, int row, int s, int lane) {
    int b = (s * 4 + (lane >> 4)) ^ (row & 7);
    return *(const half8*)(base + row * 128 + b * 16);
}

#define MF(a, b, c) __builtin_amdgcn_mfma_f32_16x16x32_f16(a, b, c, 0, 0, 0)

// ------- prep: fused x->(xhi,sq) + W1^T + W2^T (independent tiles, one launch) -------
__global__ __launch_bounds__(256) void prep_kernel(const float* __restrict__ x,
        _Float16* __restrict__ xhi, float* __restrict__ sq,
        const float* __restrict__ W1, _Float16* __restrict__ w1t,
        const float* __restrict__ W2, _Float16* __restrict__ w2t) {
    __shared__ float tile[64][65];
    int bid = blockIdx.x, tid = threadIdx.x;
    if (bid < 1568) {
        int i = bid * 4 + (tid >> 6);
        int t = tid & 63;
        const float* row = x + (size_t)i * CDIM;
        _Float16* hrow = xhi + (size_t)i * CDIM;
        float s = 0.f;
#pragma unroll
        for (int k = 0; k < 8; k++) {
            float4 v = *(const float4*)(row + (k * 64 + t) * 4);
            half4 h;
            h[0] = (_Float16)v.x; h[1] = (_Float16)v.y;
            h[2] = (_Float16)v.z; h[3] = (_Float16)v.w;
            *(half4*)(hrow + (k * 64 + t) * 4) = h;
            s += v.x * v.x + v.y * v.y + v.z * v.z + v.w * v.w;
        }
#pragma unroll
        for (int off = 32; off; off >>= 1) s += __shfl_down(s, off, 64);
        if (t == 0) sq[i] = s;
        return;
    }
    const float* W; _Float16* Wt; int K, N, idx;
    if (bid < 1824) { idx = bid - 1568; W = W1; Wt = w1t; K = CDIM; N = ODIM; }
    else            { idx = bid - 1824; W = W2; Wt = w2t; K = ODIM; N = ODIM; }
    int nkb = K / 64;
    int kb = (idx % nkb) * 64, nb = (idx / nkb) * 64;
    int r = tid >> 2, c0 = (tid & 3) * 16;
#pragma unroll
    for (int u = 0; u < 4; u++) {
        float4 v = *(const float4*)(W + (size_t)(kb + r) * N + nb + c0 + u * 4);
        tile[r][c0 + u * 4 + 0] = v.x; tile[r][c0 + u * 4 + 1] = v.y;
        tile[r][c0 + u * 4 + 2] = v.z; tile[r][c0 + u * 4 + 3] = v.w;
    }
    __syncthreads();
    int rn = tid >> 2, ck0 = (tid & 3) * 16;
#pragma unroll
    for (int u = 0; u < 4; u++) {
        half4 o;
#pragma unroll
        for (int j = 0; j < 4; j++) o[j] = (_Float16)tile[ck0 + u * 4 + j][rn];
        *(half4*)(Wt + (size_t)(nb + rn) * K + kb + ck0 + u * 4) = o;
    }
}

// ==== MERGED: gram screen (blocks 0..1231) + hgemm layer-1 (blocks 1232..1623) ====
// gram: hi-only MFMA screen, upper-tri 128x128 tiles, r13 staging (contiguous
// 128B/row lines), 4 blocks/CU. hgemm1 is INDEPENDENT (xhi @ w1t -> hw f16) and
// backfills CU slots / hides under gram's memory stalls (gram MfmaUtil ~6%).
__global__ __launch_bounds__(256, 4) void gram_hgemm_kernel(
        const _Float16* __restrict__ xhi, const float* __restrict__ sq,
        float* __restrict__ candv, unsigned short* __restrict__ candi,
        const _Float16* __restrict__ w1t, _Float16* __restrict__ hw) {
    __shared__ char lds[32768];
    int tid = threadIdx.x, lane = tid & 63, wave = tid >> 6;
    int l15 = lane & 15, kg = lane >> 4;
    int r_in = lane >> 3;
    int skb = (lane & 7) ^ r_in;

    if (blockIdx.x >= GRID_G) {
        // ---------------- hgemm layer-1: 64x128 tile, XCD-swizzled ----------------
        int hb = blockIdx.x - GRID_G;
        const int nit = N_NODES / 64;          // 98 i-tiles
        int per = GRID_H1 >> 3;                // 49
        int swz = (hb & 7) * per + (hb >> 3);
        int i0 = (swz % nit) * 64, j0 = (swz / nit) * 128;
        f32x4 acc[4][2] = {};
#pragma unroll 1
        for (int kk = 0; kk < CDIM; kk += 64) {
            __syncthreads();
#pragma unroll
            for (int g = 0; g < 6; g++) {      // 24 segs: A 8, B 16; 6 per wave
                int sg = wave * 6 + g;
                if (sg < 8) {
                    gld_lds16(xhi + (size_t)(i0 + sg * 8 + r_in) * CDIM + kk + skb * 8,
                              lds + sg * 1024);
                } else {
                    int seg = sg - 8;
                    gld_lds16(w1t + (size_t)(j0 + seg * 8 + r_in) * CDIM + kk + skb * 8,
                              lds + 8192 + seg * 1024);
                }
            }
            __syncthreads();
#pragma unroll
            for (int s = 0; s < 2; s++) {
                half8 a[4];
#pragma unroll
                for (int m = 0; m < 4; m++) a[m] = frag_read(lds, m * 16 + l15, s, lane);
#pragma unroll
                for (int n = 0; n < 2; n++) {
                    half8 b = frag_read(lds + 8192, wave * 32 + n * 16 + l15, s, lane);
#pragma unroll
                    for (int m = 0; m < 4; m++) acc[m][n] = MF(a[m], b, acc[m][n]);
                }
            }
        }
#pragma unroll
        for (int m = 0; m < 4; m++)
#pragma unroll
            for (int n = 0; n < 2; n++)
#pragma unroll
                for (int r = 0; r < 4; r++) {
                    int row = i0 + m * 16 + kg * 4 + r;
                    int colj = j0 + wave * 32 + n * 16 + l15;
                    hw[(size_t)row * ODIM + colj] = (_Float16)acc[m][n][r];
                }
        return;
    }

    // ---------------- gram screen ----------------
    float* S = (float*)lds;                                  // [128][33] 16.9KB
    float* topv = (float*)(lds + 16896);                     // [128][9]  4.6KB
    unsigned short* topi = (unsigned short*)(lds + 21504);   // [128][10] 2.6KB
#define TOPV(r, k) topv[(r) * 9 + (k)]
#define TOPI(r, k) topi[(r) * 10 + (k)]
    int wr = wave >> 1, wc = wave & 1;

    // bijective XCD chunking over t-major triangle raster (1225 = 8*153 + 1)
    int xcd = blockIdx.x & 7, loc = blockIdx.x >> 3;
    if (xcd != 0 && loc >= 153) return;
    int raster = (xcd == 0) ? loc : (154 + (xcd - 1) * 153 + loc);
    int t = (int)((sqrtf(8.f * (float)raster + 1.f) - 1.f) * 0.5f);
    while ((t + 1) * (t + 2) / 2 <= raster) t++;
    while (t * (t + 1) / 2 > raster) t--;
    int p = raster - t * (t + 1) / 2;                          // p <= t
    size_t i0 = (size_t)p * 128, j0 = (size_t)t * 128;

    f32x4 acc[4][4] = {};

#pragma unroll 1
    for (int c = 0; c < 32; c++) {
        int kk = c * 64;
#pragma unroll
        for (int g = 0; g < 8; g++) {      // 32 segs (8 rows x 128B), 8 per wave
            int sg = wave * 8 + g;
            int tI = sg >> 4, seg = sg & 15;
            size_t row = (tI ? j0 : i0) + (size_t)(seg * 8 + r_in);
            gld_lds16(xhi + row * CDIM + kk + skb * 8, lds + tI * 16384 + seg * 1024);
        }
        __syncthreads();
#pragma unroll
        for (int s = 0; s < 2; s++) {
            half8 a4[4];
#pragma unroll
            for (int m = 0; m < 4; m++)
                a4[m] = frag_read(lds, wr * 64 + m * 16 + l15, s, lane);
#pragma unroll
            for (int n = 0; n < 4; n++) {
                half8 b = frag_read(lds + 16384, wc * 64 + n * 16 + l15, s, lane);
#pragma unroll
                for (int m = 0; m < 4; m++) acc[m][n] = MF(a4[m], b, acc[m][n]);
            }
        }
        __syncthreads();
    }

    float sqi[4][4];
#pragma unroll
    for (int m = 0; m < 4; m++)
#pragma unroll
        for (int r = 0; r < 4; r++)
            sqi[m][r] = sq[(int)i0 + wr * 64 + m * 16 + kg * 4 + r];
    float sqj[4];
#pragma unroll
    for (int n = 0; n < 4; n++)
        sqj[n] = sq[(int)j0 + wc * 64 + n * 16 + l15];

    if (tid < 128) {
#pragma unroll
        for (int k = 0; k < 8; k++) { TOPV(tid, k) = 3.4e38f; TOPI(tid, k) = 0xFFFF; }
    }

    // ---- row pass ----
#pragma unroll
    for (int cs = 0; cs < 4; cs++) {
        __syncthreads();
        if (wc == (cs >> 1)) {
            const int n0 = (cs & 1) * 2;
#pragma unroll
            for (int m = 0; m < 4; m++)
#pragma unroll
                for (int nn = 0; nn < 2; nn++)
#pragma unroll
                    for (int r = 0; r < 4; r++) {
                        int row = wr * 64 + m * 16 + kg * 4 + r;
                        float d2 = sqi[m][r] + sqj[n0 + nn] - 2.f * acc[m][n0 + nn][r];
                        S[row * 33 + nn * 16 + l15] = d2;
                    }
        }
        __syncthreads();
        if (tid < 128) {
            int r = tid, gi = (int)i0 + r;
            int cbase = (int)j0 + cs * 32;
#pragma unroll 4
            for (int jj = 0; jj < 32; jj++) {
                int gj = cbase + jj;
                if (gj == gi) continue;
                float v = S[r * 33 + jj];
                float wv = TOPV(r, 7); int wi = TOPI(r, 7);
                if (v < wv || (v == wv && gj < wi)) {
                    int pos = 7;
                    while (pos > 0) {
                        float pv = TOPV(r, pos - 1); int pi = TOPI(r, pos - 1);
                        if (v < pv || (v == pv && gj < pi)) {
                            TOPV(r, pos) = pv; TOPI(r, pos) = (unsigned short)pi; pos--;
                        } else break;
                    }
                    TOPV(r, pos) = v; TOPI(r, pos) = (unsigned short)gj;
                }
            }
        }
    }
    __syncthreads();
    if (tid < 128) {
        int gi = (int)i0 + tid;
#pragma unroll
        for (int k = 0; k < 8; k++) {
            candv[(size_t)gi * NSLOT + t * 8 + k] = TOPV(tid, k);
            candi[(size_t)gi * NSLOT + t * 8 + k] = TOPI(tid, k);
        }
#pragma unroll
        for (int k = 0; k < 8; k++) { TOPV(tid, k) = 3.4e38f; TOPI(tid, k) = 0xFFFF; }
    }

    // ---- column pass (off-diagonal only) ----
    if (p < t) {
#pragma unroll
        for (int ss = 0; ss < 4; ss++) {
            __syncthreads();
            if (wr == (ss >> 1)) {
                const int mb = (ss & 1) * 2;
#pragma unroll
                for (int mm = 0; mm < 2; mm++)
#pragma unroll
                    for (int n = 0; n < 4; n++)
#pragma unroll
                        for (int r = 0; r < 4; r++) {
                            int rl  = mm * 16 + kg * 4 + r;
                            int col = wc * 64 + n * 16 + l15;
                            float d2 = sqi[mb + mm][r] + sqj[n] - 2.f * acc[mb + mm][n][r];
                            S[col * 33 + rl] = d2;
                        }
            }
            __syncthreads();
            if (tid < 128) {
                int cc = tid;
                int rbase = (int)i0 + ss * 32;
#pragma unroll 4
                for (int jj = 0; jj < 32; jj++) {
                    int gi = rbase + jj;
                    float v = S[cc * 33 + jj];
                    float wv = TOPV(cc, 7); int wi = TOPI(cc, 7);
                    if (v < wv || (v == wv && gi < wi)) {
                        int pos = 7;
                        while (pos > 0) {
                            float pv = TOPV(cc, pos - 1); int pi = TOPI(cc, pos - 1);
                            if (v < pv || (v == pv && gi < pi)) {
                                TOPV(cc, pos) = pv; TOPI(cc, pos) = (unsigned short)pi; pos--;
                            } else break;
                        }
                        TOPV(cc, pos) = v; TOPI(cc, pos) = (unsigned short)gi;
                    }
                }
            }
        }
        __syncthreads();
        if (tid < 128) {
            int gj = (int)j0 + tid;
#pragma unroll
            for (int k = 0; k < 8; k++) {
                candv[(size_t)gj * NSLOT + p * 8 + k] = TOPV(tid, k);
                candi[(size_t)gj * NSLOT + p * 8 + k] = TOPI(tid, k);
            }
        }
    }
#undef TOPV
#undef TOPI
}

// --- fused: merge 49 lists -> approx top-16 -> gated exact refine -> knn top-8 ---
__global__ __launch_bounds__(256) void knn_select_kernel(
        const float* __restrict__ candv, const unsigned short* __restrict__ candi,
        const float* __restrict__ x, const float* __restrict__ sq,
        int* __restrict__ knn) {
    int node = blockIdx.x * 4 + (threadIdx.x >> 6);
    int lane = threadIdx.x & 63;
    const float* cv = candv + (size_t)node * NSLOT;
    const unsigned short* ci = candi + (size_t)node * NSLOT;
    float v[7]; int ix[7];
#pragma unroll
    for (int u = 0; u < 7; u++) {
        int s = u * 64 + lane;
        bool ok = (s < NSLOT);
        v[u]  = ok ? cv[s] : 3.4e38f;
        ix[u] = ok ? (int)ci[s] : 0x7fffffff;
    }
    float myv16 = 3.4e38f; int myc = 0x7fffffff;
#pragma unroll 1
    for (int k = 0; k < 16; k++) {
        float bv = v[0]; int bi = ix[0];
#pragma unroll
        for (int u = 1; u < 7; u++)
            if (v[u] < bv || (v[u] == bv && ix[u] < bi)) { bv = v[u]; bi = ix[u]; }
#pragma unroll
        for (int off = 32; off; off >>= 1) {
            float ov = __shfl_xor(bv, off, 64);
            int   oi = __shfl_xor(bi, off, 64);
            if (ov < bv || (ov == bv && oi < bi)) { bv = ov; bi = oi; }
        }
        if (lane == k) { myv16 = bv; myc = bi; }
#pragma unroll
        for (int u = 0; u < 7; u++)
            if (ix[u] == bi) { v[u] = 3.4e38f; ix[u] = 0x7fffffff; }
    }
    float g7 = __shfl(myv16, 7, 64), g8 = __shfl(myv16, 8, 64);
    if (g8 - g7 > GATE) {
        if (lane < 8) knn[(size_t)node * 8 + lane] = myc;
        return;
    }
    const float* xi = x + (size_t)node * CDIM;
    float4 a[8];
#pragma unroll
    for (int g = 0; g < 8; g++) a[g] = *(const float4*)(xi + (g * 64 + lane) * 4);
    float sqi = sq[node];
    float rv = 3.4e38f; int ri = 0x7fffffff;
#pragma unroll 1
    for (int c = 0; c < 16; c++) {
        int j = __shfl(myc, c, 64);
        const float* xj = x + (size_t)j * CDIM;
        float s = 0.f;
#pragma unroll
        for (int g = 0; g < 8; g++) {
            float4 b = *(const float4*)(xj + (g * 64 + lane) * 4);
            s = fmaf(a[g].x, b.x, s); s = fmaf(a[g].y, b.y, s);
            s = fmaf(a[g].z, b.z, s); s = fmaf(a[g].w, b.w, s);
        }
#pragma unroll
        for (int off = 32; off; off >>= 1) s += __shfl_down(s, off, 64);
        float d2 = sqi + sq[j] - 2.f * s;
        d2 = __shfl(d2, 0, 64);
        if (lane == c) { rv = d2; ri = j; }
    }
#pragma unroll 1
    for (int k = 0; k < 8; k++) {
        float bv = rv; int bi = ri;
#pragma unroll
        for (int off = 8; off; off >>= 1) {
            float ov = __shfl_xor(bv, off, 64);
            int   oi = __shfl_xor(bi, off, 64);
            if (ov < bv || (ov == bv && oi < bi)) { bv = ov; bi = oi; }
        }
        bv = __shfl(bv, lane & 15, 64); bi = __shfl(bi, lane & 15, 64);
        if (lane == 0) knn[(size_t)node * 8 + k] = bi;
        if (ri == bi) { rv = 3.4e38f; ri = 0x7fffffff; }
    }
}

// ---- graph build, single block: deg/cnt/rptr in LDS, one launch -----
__global__ __launch_bounds__(1024) void graph_build_kernel(
        const int* __restrict__ knn, float* __restrict__ dinv,
        int* __restrict__ row_ptr, int* __restrict__ col) {
    __shared__ int deg_l[N_NODES];
    __shared__ int cnt_l[N_NODES];
    __shared__ int rp_l[N_NODES];
    __shared__ int partial[1024];
    int tid = threadIdx.x;
    for (int i = tid; i < N_NODES; i += 1024) { deg_l[i] = 1; cnt_l[i] = 0; }
    __syncthreads();
    for (int e = tid; e < N_NODES * 8; e += 1024) atomicAdd(&deg_l[knn[e]], 1);
    __syncthreads();
    const int CH = 7;
    int start = tid * CH;
    int end = start + CH; if (end > N_NODES) end = N_NODES;
    int s = 0;
    for (int i = start; i < end; i++) s += deg_l[i];
    partial[tid] = s;
    __syncthreads();
    if (tid == 0) {
        int run = 0;
        for (int k = 0; k < 1024; k++) { int vv = partial[k]; partial[k] = run; run += vv; }
        row_ptr[N_NODES] = run;
    }
    __syncthreads();
    int run = partial[tid];
    for (int i = start; i < end; i++) {
        rp_l[i] = run; row_ptr[i] = run;
        dinv[i] = rsqrtf((float)deg_l[i]);
        run += deg_l[i];
    }
    __syncthreads();
    for (int i = tid; i < N_NODES; i += 1024) {
        int p0 = rp_l[i] + atomicAdd(&cnt_l[i], 1);
        col[p0] = i;
#pragma unroll
        for (int j = 0; j < 8; j++) {
            int d = knn[i * 8 + j];
            int q = rp_l[d] + atomicAdd(&cnt_l[d], 1);
            col[q] = i;
        }
    }
}

// ---- fp16 MFMA GEMM, 64x128 tiles, f16 out, XCD-swizzled (layer 2) ----
__global__ __launch_bounds__(256) void hgemm_nt_kernel(
        const _Float16* __restrict__ A, const _Float16* __restrict__ Bt,
        _Float16* __restrict__ C, int M, int N, int K) {
    __shared__ char lds[24576];        // A 8KB | B 16KB
    int tid = threadIdx.x, lane = tid & 63, wave = tid >> 6;
    int l15 = lane & 15, kg = lane >> 4;
    int nt = N >> 7;
    int nblk = (M >> 6) * nt;
    int per = nblk >> 3;
    int swz = (blockIdx.x & 7) * per + (blockIdx.x >> 3);
    int i0 = (swz % (M >> 6)) * 64, j0 = (swz / (M >> 6)) * 128;
    f32x4 acc[4][2] = {};

    int r_in = lane >> 3;
    int skb = (lane & 7) ^ r_in;

#pragma unroll 1
    for (int kk = 0; kk < K; kk += 64) {
        __syncthreads();
#pragma unroll
        for (int g = 0; g < 6; g++) {
            int sg = wave * 6 + g;
            if (sg < 8) {
                gld_lds16(A + (size_t)(i0 + sg * 8 + r_in) * K + kk + skb * 8,
                          lds + sg * 1024);
            } else {
                int seg = sg - 8;
                gld_lds16(Bt + (size_t)(j0 + seg * 8 + r_in) * K + kk + skb * 8,
                          lds + 8192 + seg * 1024);
            }
        }
        __syncthreads();
#pragma unroll
        for (int s = 0; s < 2; s++) {
            half8 a[4];
#pragma unroll
            for (int m = 0; m < 4; m++) a[m] = frag_read(lds, m * 16 + l15, s, lane);
#pragma unroll
            for (int n = 0; n < 2; n++) {
                half8 b = frag_read(lds + 8192, wave * 32 + n * 16 + l15, s, lane);
#pragma unroll
                for (int m = 0; m < 4; m++) acc[m][n] = MF(a[m], b, acc[m][n]);
            }
        }
    }
#pragma unroll
    for (int m = 0; m < 4; m++)
#pragma unroll
        for (int n = 0; n < 2; n++)
#pragma unroll
            for (int r = 0; r < 4; r++) {
                int row = i0 + m * 16 + kg * 4 + r;
                int colj = j0 + wave * 32 + n * 16 + l15;
                C[(size_t)row * N + colj] = (_Float16)acc[m][n][r];
            }
}

// --- GCN aggregation (f16 in): out[d] = relu(dinv[d]*sum hw[s]*dinv[s] + b) ---
template <bool HALF_OUT>
__global__ __launch_bounds__(256) void aggregate_kernel(
        const _Float16* __restrict__ hw, const int* __restrict__ row_ptr,
        const int* __restrict__ col, const float* __restrict__ dinv,
        const float* __restrict__ bias, void* __restrict__ outp) {
    int node = blockIdx.x * 4 + (threadIdx.x >> 6);
    int lane = threadIdx.x & 63;
    int e0 = row_ptr[node], e1 = row_ptr[node + 1];
    float acc[8] = {};
    for (int e = e0; e < e1; e++) {
        int s = col[e];
        float w = dinv[s];
        half8 v = *(const half8*)(hw + (size_t)s * ODIM + lane * 8);
#pragma unroll
        for (int j = 0; j < 8; j++) acc[j] = fmaf(w, (float)v[j], acc[j]);
    }
    float wd = dinv[node];
    float4 b0 = *(const float4*)(bias + lane * 8);
    float4 b1 = *(const float4*)(bias + lane * 8 + 4);
    float o[8];
    o[0] = fmaxf(fmaf(acc[0], wd, b0.x), 0.f);
    o[1] = fmaxf(fmaf(acc[1], wd, b0.y), 0.f);
    o[2] = fmaxf(fmaf(acc[2], wd, b0.z), 0.f);
    o[3] = fmaxf(fmaf(acc[3], wd, b0.w), 0.f);
    o[4] = fmaxf(fmaf(acc[4], wd, b1.x), 0.f);
    o[5] = fmaxf(fmaf(acc[5], wd, b1.y), 0.f);
    o[6] = fmaxf(fmaf(acc[6], wd, b1.z), 0.f);
    o[7] = fmaxf(fmaf(acc[7], wd, b1.w), 0.f);
    if (HALF_OUT) {
        half8 h;
#pragma unroll
        for (int j = 0; j < 8; j++) h[j] = (_Float16)o[j];
        *(half8*)((_Float16*)outp + (size_t)node * ODIM + lane * 8) = h;
    } else {
        float* out = (float*)outp;
        float4 f0 = {o[0], o[1], o[2], o[3]}, f1 = {o[4], o[5], o[6], o[7]};
        *(float4*)(out + (size_t)node * ODIM + lane * 8)     = f0;
        *(float4*)(out + (size_t)node * ODIM + lane * 8 + 4) = f1;
    }
}

extern "C" void kernel_launch(void* const* d_in, const int* in_sizes, int n_in,
                              void* d_out, int out_size, void* d_ws, size_t ws_size,
                              hipStream_t stream) {
    const float* x  = (const float*)d_in[0];
    const float* W1 = (const float*)d_in[1];
    const float* b1 = (const float*)d_in[2];
    const float* W2 = (const float*)d_in[3];
    const float* b2 = (const float*)d_in[4];
    float* out = (float*)d_out;
    char* ws = (char*)d_ws;

    _Float16* xhi  = (_Float16*)(ws + XHI_OFF);
    float* candv   = (float*)(ws + CANDV_OFF);
    unsigned short* candi = (unsigned short*)(ws + CANDI_OFF);
    float* sq      = (float*)(ws + SQ_OFF);
    int*   knn     = (int*)  (ws + KNN_OFF);
    float* dinv    = (float*)(ws + DINV_OFF);
    int*   row_ptr = (int*)  (ws + RPTR_OFF);
    int*   col     = (int*)  (ws + COL_OFF);
    _Float16* w1t  = (_Float16*)(ws + W1T_OFF);
    _Float16* w2t  = (_Float16*)(ws + W2T_OFF);
    _Float16* hw   = (_Float16*)(ws + HW_OFF);
    _Float16* h1h  = (_Float16*)(ws + H1H_OFF);

    prep_kernel<<<1888, 256, 0, stream>>>(x, xhi, sq, W1, w1t, W2, w2t);
    gram_hgemm_kernel<<<GRID_G + GRID_H1, 256, 0, stream>>>(xhi, sq, candv, candi, w1t, hw);
    knn_select_kernel<<<N_NODES / 4, 256, 0, stream>>>(candv, candi, x, sq, knn);
    graph_build_kernel<<<1, 1024, 0, stream>>>(knn, dinv, row_ptr, col);

    aggregate_kernel<true><<<N_NODES / 4, 256, 0, stream>>>(hw, row_ptr, col, dinv, b1, (void*)h1h);
    hgemm_nt_kernel<<<(N_NODES / 64) * (ODIM / 128), 256, 0, stream>>>(h1h, w2t, hw, N_NODES, ODIM, ODIM);
    aggregate_kernel<false><<<N_NODES / 4, 256, 0, stream>>>(hw, row_ptr, col, dinv, b2, (void*)out);
}

// Round 17
// 1079.153 us; speedup vs baseline: 1.6226x; 1.0195x over previous
//
#include <hip/hip_runtime.h>

typedef __attribute__((ext_vector_type(8))) _Float16 half8;
typedef __attribute__((ext_vector_type(4))) _Float16 half4;
typedef __attribute__((ext_vector_type(4))) float f32x4;

#define N_NODES 6272
#define CDIM    2048
#define ODIM    512
#define NPAN    49       // 6272 / 128 node panels
#define NSLOT   392      // 49 panels * 8 candidates per node
#define GRID_G  1232     // 8 x 154 (1225 live triangle tiles + 7 dead)
#define GRID_H1 392      // hgemm layer-1 blocks (64x128 tiles)
#define E2      0.5f     // 2*E, E=0.25 ~ 7 sigma of hi-only screen d2 error

// ---------------- workspace layout (bytes) ----------------
#define XHI_OFF    0ul                 // 25,690,112
#define CANDV_OFF  25690112ul          // 6272*392*4 = 9,834,496
#define CANDI_OFF  35524608ul          // 6272*392*2 = 4,917,248
#define SQ_OFF     40441856ul
#define KNN_OFF    40466944ul
#define DINV_OFF   41520640ul
#define RPTR_OFF   41545728ul
#define COL_OFF    41571072ul
#define W1T_OFF    41796864ul
#define W2T_OFF    43894016ul          // -> 44,418,304
#define H1H_OFF    44418304ul          // f16 6.4MB -> 50,843,648
#define HW_OFF     50843648ul          // f16 6.4MB (own region: gram writes candv
                                       // concurrently with hgemm1 writing hw)

// ---------------- async global->LDS (16B per lane, wave-uniform LDS base) ----
__device__ __forceinline__ void gld_lds16(const void* g, void* l) {
    __builtin_amdgcn_global_load_lds(
        (const __attribute__((address_space(1))) void*)g,
        (__attribute__((address_space(3))) void*)l, 16, 0, 0);
}

// BK=64 tile: [row][128B]; 16B slot b holds logical k-block b ^ (row&7).
__device__ __forceinline__ half8 frag_read(const char* base, int row, int s, int lane) {
    int b = (s * 4 + (lane >> 4)) ^ (row & 7);
    return *(const half8*)(base + row * 128 + b * 16);
}

#define MF(a, b, c) __builtin_amdgcn_mfma_f32_16x16x32_f16(a, b, c, 0, 0, 0)

// ------- prep: fused x->(xhi,sq) + W1^T + W2^T (independent tiles, one launch) -------
__global__ __launch_bounds__(256) void prep_kernel(const float* __restrict__ x,
        _Float16* __restrict__ xhi, float* __restrict__ sq,
        const float* __restrict__ W1, _Float16* __restrict__ w1t,
        const float* __restrict__ W2, _Float16* __restrict__ w2t) {
    __shared__ float tile[64][65];
    int bid = blockIdx.x, tid = threadIdx.x;
    if (bid < 1568) {
        int i = bid * 4 + (tid >> 6);
        int t = tid & 63;
        const float* row = x + (size_t)i * CDIM;
        _Float16* hrow = xhi + (size_t)i * CDIM;
        float s = 0.f;
#pragma unroll
        for (int k = 0; k < 8; k++) {
            float4 v = *(const float4*)(row + (k * 64 + t) * 4);
            half4 h;
            h[0] = (_Float16)v.x; h[1] = (_Float16)v.y;
            h[2] = (_Float16)v.z; h[3] = (_Float16)v.w;
            *(half4*)(hrow + (k * 64 + t) * 4) = h;
            s += v.x * v.x + v.y * v.y + v.z * v.z + v.w * v.w;
        }
#pragma unroll
        for (int off = 32; off; off >>= 1) s += __shfl_down(s, off, 64);
        if (t == 0) sq[i] = s;
        return;
    }
    const float* W; _Float16* Wt; int K, N, idx;
    if (bid < 1824) { idx = bid - 1568; W = W1; Wt = w1t; K = CDIM; N = ODIM; }
    else            { idx = bid - 1824; W = W2; Wt = w2t; K = ODIM; N = ODIM; }
    int nkb = K / 64;
    int kb = (idx % nkb) * 64, nb = (idx / nkb) * 64;
    int r = tid >> 2, c0 = (tid & 3) * 16;
#pragma unroll
    for (int u = 0; u < 4; u++) {
        float4 v = *(const float4*)(W + (size_t)(kb + r) * N + nb + c0 + u * 4);
        tile[r][c0 + u * 4 + 0] = v.x; tile[r][c0 + u * 4 + 1] = v.y;
        tile[r][c0 + u * 4 + 2] = v.z; tile[r][c0 + u * 4 + 3] = v.w;
    }
    __syncthreads();
    int rn = tid >> 2, ck0 = (tid & 3) * 16;
#pragma unroll
    for (int u = 0; u < 4; u++) {
        half4 o;
#pragma unroll
        for (int j = 0; j < 4; j++) o[j] = (_Float16)tile[ck0 + u * 4 + j][rn];
        *(half4*)(Wt + (size_t)(nb + rn) * K + kb + ck0 + u * 4) = o;
    }
}

// ==== MERGED: gram screen (blocks 0..1231) + hgemm layer-1 (blocks 1232..1623) ====
__global__ __launch_bounds__(256, 4) void gram_hgemm_kernel(
        const _Float16* __restrict__ xhi, const float* __restrict__ sq,
        float* __restrict__ candv, unsigned short* __restrict__ candi,
        const _Float16* __restrict__ w1t, _Float16* __restrict__ hw) {
    __shared__ char lds[32768];
    int tid = threadIdx.x, lane = tid & 63, wave = tid >> 6;
    int l15 = lane & 15, kg = lane >> 4;
    int r_in = lane >> 3;
    int skb = (lane & 7) ^ r_in;

    if (blockIdx.x >= GRID_G) {
        // ---------------- hgemm layer-1: 64x128 tile, XCD-swizzled ----------------
        int hb = blockIdx.x - GRID_G;
        const int nit = N_NODES / 64;          // 98 i-tiles
        int per = GRID_H1 >> 3;                // 49
        int swz = (hb & 7) * per + (hb >> 3);
        int i0 = (swz % nit) * 64, j0 = (swz / nit) * 128;
        f32x4 acc[4][2] = {};
#pragma unroll 1
        for (int kk = 0; kk < CDIM; kk += 64) {
            __syncthreads();
#pragma unroll
            for (int g = 0; g < 6; g++) {      // 24 segs: A 8, B 16; 6 per wave
                int sg = wave * 6 + g;
                if (sg < 8) {
                    gld_lds16(xhi + (size_t)(i0 + sg * 8 + r_in) * CDIM + kk + skb * 8,
                              lds + sg * 1024);
                } else {
                    int seg = sg - 8;
                    gld_lds16(w1t + (size_t)(j0 + seg * 8 + r_in) * CDIM + kk + skb * 8,
                              lds + 8192 + seg * 1024);
                }
            }
            __syncthreads();
#pragma unroll
            for (int s = 0; s < 2; s++) {
                half8 a[4];
#pragma unroll
                for (int m = 0; m < 4; m++) a[m] = frag_read(lds, m * 16 + l15, s, lane);
#pragma unroll
                for (int n = 0; n < 2; n++) {
                    half8 b = frag_read(lds + 8192, wave * 32 + n * 16 + l15, s, lane);
#pragma unroll
                    for (int m = 0; m < 4; m++) acc[m][n] = MF(a[m], b, acc[m][n]);
                }
            }
        }
#pragma unroll
        for (int m = 0; m < 4; m++)
#pragma unroll
            for (int n = 0; n < 2; n++)
#pragma unroll
                for (int r = 0; r < 4; r++) {
                    int row = i0 + m * 16 + kg * 4 + r;
                    int colj = j0 + wave * 32 + n * 16 + l15;
                    hw[(size_t)row * ODIM + colj] = (_Float16)acc[m][n][r];
                }
        return;
    }

    // ---------------- gram screen ----------------
    float* S = (float*)lds;                                  // [128][33] 16.9KB
    float* topv = (float*)(lds + 16896);                     // [128][9]  4.6KB
    unsigned short* topi = (unsigned short*)(lds + 21504);   // [128][10] 2.6KB
#define TOPV(r, k) topv[(r) * 9 + (k)]
#define TOPI(r, k) topi[(r) * 10 + (k)]
    int wr = wave >> 1, wc = wave & 1;

    // bijective XCD chunking over t-major triangle raster (1225 = 8*153 + 1)
    int xcd = blockIdx.x & 7, loc = blockIdx.x >> 3;
    if (xcd != 0 && loc >= 153) return;
    int raster = (xcd == 0) ? loc : (154 + (xcd - 1) * 153 + loc);
    int t = (int)((sqrtf(8.f * (float)raster + 1.f) - 1.f) * 0.5f);
    while ((t + 1) * (t + 2) / 2 <= raster) t++;
    while (t * (t + 1) / 2 > raster) t--;
    int p = raster - t * (t + 1) / 2;                          // p <= t
    size_t i0 = (size_t)p * 128, j0 = (size_t)t * 128;

    f32x4 acc[4][4] = {};

#pragma unroll 1
    for (int c = 0; c < 32; c++) {
        int kk = c * 64;
#pragma unroll
        for (int g = 0; g < 8; g++) {      // 32 segs (8 rows x 128B), 8 per wave
            int sg = wave * 8 + g;
            int tI = sg >> 4, seg = sg & 15;
            size_t row = (tI ? j0 : i0) + (size_t)(seg * 8 + r_in);
            gld_lds16(xhi + row * CDIM + kk + skb * 8, lds + tI * 16384 + seg * 1024);
        }
        __syncthreads();
#pragma unroll
        for (int s = 0; s < 2; s++) {
            half8 a4[4];
#pragma unroll
            for (int m = 0; m < 4; m++)
                a4[m] = frag_read(lds, wr * 64 + m * 16 + l15, s, lane);
#pragma unroll
            for (int n = 0; n < 4; n++) {
                half8 b = frag_read(lds + 16384, wc * 64 + n * 16 + l15, s, lane);
#pragma unroll
                for (int m = 0; m < 4; m++) acc[m][n] = MF(a4[m], b, acc[m][n]);
            }
        }
        __syncthreads();
    }

    float sqi[4][4];
#pragma unroll
    for (int m = 0; m < 4; m++)
#pragma unroll
        for (int r = 0; r < 4; r++)
            sqi[m][r] = sq[(int)i0 + wr * 64 + m * 16 + kg * 4 + r];
    float sqj[4];
#pragma unroll
    for (int n = 0; n < 4; n++)
        sqj[n] = sq[(int)j0 + wc * 64 + n * 16 + l15];

    if (tid < 128) {
#pragma unroll
        for (int k = 0; k < 8; k++) { TOPV(tid, k) = 3.4e38f; TOPI(tid, k) = 0xFFFF; }
    }

    // ---- row pass ----
#pragma unroll
    for (int cs = 0; cs < 4; cs++) {
        __syncthreads();
        if (wc == (cs >> 1)) {
            const int n0 = (cs & 1) * 2;
#pragma unroll
            for (int m = 0; m < 4; m++)
#pragma unroll
                for (int nn = 0; nn < 2; nn++)
#pragma unroll
                    for (int r = 0; r < 4; r++) {
                        int row = wr * 64 + m * 16 + kg * 4 + r;
                        float d2 = sqi[m][r] + sqj[n0 + nn] - 2.f * acc[m][n0 + nn][r];
                        S[row * 33 + nn * 16 + l15] = d2;
                    }
        }
        __syncthreads();
        if (tid < 128) {
            int r = tid, gi = (int)i0 + r;
            int cbase = (int)j0 + cs * 32;
#pragma unroll 4
            for (int jj = 0; jj < 32; jj++) {
                int gj = cbase + jj;
                if (gj == gi) continue;
                float v = S[r * 33 + jj];
                float wv = TOPV(r, 7); int wi = TOPI(r, 7);
                if (v < wv || (v == wv && gj < wi)) {
                    int pos = 7;
                    while (pos > 0) {
                        float pv = TOPV(r, pos - 1); int pi = TOPI(r, pos - 1);
                        if (v < pv || (v == pv && gj < pi)) {
                            TOPV(r, pos) = pv; TOPI(r, pos) = (unsigned short)pi; pos--;
                        } else break;
                    }
                    TOPV(r, pos) = v; TOPI(r, pos) = (unsigned short)gj;
                }
            }
        }
    }
    __syncthreads();
    if (tid < 128) {
        int gi = (int)i0 + tid;
#pragma unroll
        for (int k = 0; k < 8; k++) {
            candv[(size_t)gi * NSLOT + t * 8 + k] = TOPV(tid, k);
            candi[(size_t)gi * NSLOT + t * 8 + k] = TOPI(tid, k);
        }
#pragma unroll
        for (int k = 0; k < 8; k++) { TOPV(tid, k) = 3.4e38f; TOPI(tid, k) = 0xFFFF; }
    }

    // ---- column pass (off-diagonal only) ----
    if (p < t) {
#pragma unroll
        for (int ss = 0; ss < 4; ss++) {
            __syncthreads();
            if (wr == (ss >> 1)) {
                const int mb = (ss & 1) * 2;
#pragma unroll
                for (int mm = 0; mm < 2; mm++)
#pragma unroll
                    for (int n = 0; n < 4; n++)
#pragma unroll
                        for (int r = 0; r < 4; r++) {
                            int rl  = mm * 16 + kg * 4 + r;
                            int col = wc * 64 + n * 16 + l15;
                            float d2 = sqi[mb + mm][r] + sqj[n] - 2.f * acc[mb + mm][n][r];
                            S[col * 33 + rl] = d2;
                        }
            }
            __syncthreads();
            if (tid < 128) {
                int cc = tid;
                int rbase = (int)i0 + ss * 32;
#pragma unroll 4
                for (int jj = 0; jj < 32; jj++) {
                    int gi = rbase + jj;
                    float v = S[cc * 33 + jj];
                    float wv = TOPV(cc, 7); int wi = TOPI(cc, 7);
                    if (v < wv || (v == wv && gi < wi)) {
                        int pos = 7;
                        while (pos > 0) {
                            float pv = TOPV(cc, pos - 1); int pi = TOPI(cc, pos - 1);
                            if (v < pv || (v == pv && gi < pi)) {
                                TOPV(cc, pos) = pv; TOPI(cc, pos) = (unsigned short)pi; pos--;
                            } else break;
                        }
                        TOPV(cc, pos) = v; TOPI(cc, pos) = (unsigned short)gi;
                    }
                }
            }
        }
        __syncthreads();
        if (tid < 128) {
            int gj = (int)j0 + tid;
#pragma unroll
            for (int k = 0; k < 8; k++) {
                candv[(size_t)gj * NSLOT + p * 8 + k] = TOPV(tid, k);
                candi[(size_t)gj * NSLOT + p * 8 + k] = TOPI(tid, k);
            }
        }
    }
#undef TOPV
#undef TOPI
}

// --- fused: merge 49 lists -> approx top-16 -> BAND-limited exact refine -> knn ---
// Set semantics (aggregation is permutation-invariant): candidate certainly-IN if
// v < v7-E2 (exact < v7-E while all others' exact > v7-E); certainly-OUT if
// v > v8+E2. Only band candidates need the exact fp32 dot (typically 0-3).
__global__ __launch_bounds__(256) void knn_select_kernel(
        const float* __restrict__ candv, const unsigned short* __restrict__ candi,
        const float* __restrict__ x, const float* __restrict__ sq,
        int* __restrict__ knn) {
    int node = blockIdx.x * 4 + (threadIdx.x >> 6);
    int lane = threadIdx.x & 63;
    const float* cv = candv + (size_t)node * NSLOT;
    const unsigned short* ci = candi + (size_t)node * NSLOT;
    float v[7]; int ix[7];
#pragma unroll
    for (int u = 0; u < 7; u++) {
        int s = u * 64 + lane;
        bool ok = (s < NSLOT);
        v[u]  = ok ? cv[s] : 3.4e38f;
        ix[u] = ok ? (int)ci[s] : 0x7fffffff;
    }
    float myv16 = 3.4e38f; int myc = 0x7fffffff;   // lane k<16 owns k-th candidate
#pragma unroll 1
    for (int k = 0; k < 16; k++) {
        float bv = v[0]; int bi = ix[0];
#pragma unroll
        for (int u = 1; u < 7; u++)
            if (v[u] < bv || (v[u] == bv && ix[u] < bi)) { bv = v[u]; bi = ix[u]; }
#pragma unroll
        for (int off = 32; off; off >>= 1) {
            float ov = __shfl_xor(bv, off, 64);
            int   oi = __shfl_xor(bi, off, 64);
            if (ov < bv || (ov == bv && oi < bi)) { bv = ov; bi = oi; }
        }
        if (lane == k) { myv16 = bv; myc = bi; }
#pragma unroll
        for (int u = 0; u < 7; u++)
            if (ix[u] == bi) { v[u] = 3.4e38f; ix[u] = 0x7fffffff; }
    }
    float v7 = __shfl(myv16, 7, 64), v8 = __shfl(myv16, 8, 64);
    if (v8 - v7 > E2) {                            // fast path: set provably exact
        if (lane < 8) knn[(size_t)node * 8 + lane] = myc;
        return;
    }
    // band classification
    bool isc  = (lane < 16);
    bool cin  = isc && (myv16 < v7 - E2);
    bool cout = isc && (myv16 > v8 + E2);
    bool band = isc && !cin && !cout;
    unsigned long long bm = __ballot(band);
    float fv = myv16;
    if (cin)  fv = myv16 - 1e9f;                   // sorts first (always selected)
    if (cout) fv = myv16 + 1e9f;                   // sorts last (never selected)

    const float* xi = x + (size_t)node * CDIM;
    float4 a[8];
#pragma unroll
    for (int g = 0; g < 8; g++) a[g] = *(const float4*)(xi + (g * 64 + lane) * 4);
    float sqi = sq[node];
#pragma unroll 1
    for (int c = 0; c < 16; c++) {
        if (!((bm >> c) & 1ull)) continue;         // wave-uniform skip
        int j = __shfl(myc, c, 64);
        const float* xj = x + (size_t)j * CDIM;
        float s = 0.f;
#pragma unroll
        for (int g = 0; g < 8; g++) {
            float4 b = *(const float4*)(xj + (g * 64 + lane) * 4);
            s = fmaf(a[g].x, b.x, s); s = fmaf(a[g].y, b.y, s);
            s = fmaf(a[g].z, b.z, s); s = fmaf(a[g].w, b.w, s);
        }
#pragma unroll
        for (int off = 32; off; off >>= 1) s += __shfl_down(s, off, 64);
        float d2 = sqi + sq[j] - 2.f * s;
        d2 = __shfl(d2, 0, 64);
        if (lane == c) fv = d2;                    // exact value for band member
    }
    // select 8 smallest (fv, idx) among the 16 candidates
    float rv = (lane < 16) ? fv : 3.4e38f;
    int   ri = (lane < 16) ? myc : 0x7fffffff;
#pragma unroll 1
    for (int k = 0; k < 8; k++) {
        float bv = rv; int bi = ri;
#pragma unroll
        for (int off = 8; off; off >>= 1) {        // butterfly over lanes 0..15
            float ov = __shfl_xor(bv, off, 64);
            int   oi = __shfl_xor(bi, off, 64);
            if (ov < bv || (ov == bv && oi < bi)) { bv = ov; bi = oi; }
        }
        bv = __shfl(bv, lane & 15, 64); bi = __shfl(bi, lane & 15, 64);
        if (lane == 0) knn[(size_t)node * 8 + k] = bi;
        if (ri == bi) { rv = 3.4e38f; ri = 0x7fffffff; }
    }
}

// ---- graph build, single block: deg/cnt/rptr in LDS, one launch -----
__global__ __launch_bounds__(1024) void graph_build_kernel(
        const int* __restrict__ knn, float* __restrict__ dinv,
        int* __restrict__ row_ptr, int* __restrict__ col) {
    __shared__ int deg_l[N_NODES];
    __shared__ int cnt_l[N_NODES];
    __shared__ int rp_l[N_NODES];
    __shared__ int partial[1024];
    int tid = threadIdx.x;
    for (int i = tid; i < N_NODES; i += 1024) { deg_l[i] = 1; cnt_l[i] = 0; }
    __syncthreads();
    for (int e = tid; e < N_NODES * 8; e += 1024) atomicAdd(&deg_l[knn[e]], 1);
    __syncthreads();
    const int CH = 7;
    int start = tid * CH;
    int end = start + CH; if (end > N_NODES) end = N_NODES;
    int s = 0;
    for (int i = start; i < end; i++) s += deg_l[i];
    partial[tid] = s;
    __syncthreads();
    if (tid == 0) {
        int run = 0;
        for (int k = 0; k < 1024; k++) { int vv = partial[k]; partial[k] = run; run += vv; }
        row_ptr[N_NODES] = run;
    }
    __syncthreads();
    int run = partial[tid];
    for (int i = start; i < end; i++) {
        rp_l[i] = run; row_ptr[i] = run;
        dinv[i] = rsqrtf((float)deg_l[i]);
        run += deg_l[i];
    }
    __syncthreads();
    for (int i = tid; i < N_NODES; i += 1024) {
        int p0 = rp_l[i] + atomicAdd(&cnt_l[i], 1);
        col[p0] = i;
#pragma unroll
        for (int j = 0; j < 8; j++) {
            int d = knn[i * 8 + j];
            int q = rp_l[d] + atomicAdd(&cnt_l[d], 1);
            col[q] = i;
        }
    }
}

// ---- fp16 MFMA GEMM, 64x128 tiles, f16 out, XCD-swizzled (layer 2) ----
__global__ __launch_bounds__(256) void hgemm_nt_kernel(
        const _Float16* __restrict__ A, const _Float16* __restrict__ Bt,
        _Float16* __restrict__ C, int M, int N, int K) {
    __shared__ char lds[24576];        // A 8KB | B 16KB
    int tid = threadIdx.x, lane = tid & 63, wave = tid >> 6;
    int l15 = lane & 15, kg = lane >> 4;
    int nt = N >> 7;
    int nblk = (M >> 6) * nt;
    int per = nblk >> 3;
    int swz = (blockIdx.x & 7) * per + (blockIdx.x >> 3);
    int i0 = (swz % (M >> 6)) * 64, j0 = (swz / (M >> 6)) * 128;
    f32x4 acc[4][2] = {};

    int r_in = lane >> 3;
    int skb = (lane & 7) ^ r_in;

#pragma unroll 1
    for (int kk = 0; kk < K; kk += 64) {
        __syncthreads();
#pragma unroll
        for (int g = 0; g < 6; g++) {
            int sg = wave * 6 + g;
            if (sg < 8) {
                gld_lds16(A + (size_t)(i0 + sg * 8 + r_in) * K + kk + skb * 8,
                          lds + sg * 1024);
            } else {
                int seg = sg - 8;
                gld_lds16(Bt + (size_t)(j0 + seg * 8 + r_in) * K + kk + skb * 8,
                          lds + 8192 + seg * 1024);
            }
        }
        __syncthreads();
#pragma unroll
        for (int s = 0; s < 2; s++) {
            half8 a[4];
#pragma unroll
            for (int m = 0; m < 4; m++) a[m] = frag_read(lds, m * 16 + l15, s, lane);
#pragma unroll
            for (int n = 0; n < 2; n++) {
                half8 b = frag_read(lds + 8192, wave * 32 + n * 16 + l15, s, lane);
#pragma unroll
                for (int m = 0; m < 4; m++) acc[m][n] = MF(a[m], b, acc[m][n]);
            }
        }
    }
#pragma unroll
    for (int m = 0; m < 4; m++)
#pragma unroll
        for (int n = 0; n < 2; n++)
#pragma unroll
            for (int r = 0; r < 4; r++) {
                int row = i0 + m * 16 + kg * 4 + r;
                int colj = j0 + wave * 32 + n * 16 + l15;
                C[(size_t)row * N + colj] = (_Float16)acc[m][n][r];
            }
}

// --- GCN aggregation (f16 in): out[d] = relu(dinv[d]*sum hw[s]*dinv[s] + b) ---
template <bool HALF_OUT>
__global__ __launch_bounds__(256) void aggregate_kernel(
        const _Float16* __restrict__ hw, const int* __restrict__ row_ptr,
        const int* __restrict__ col, const float* __restrict__ dinv,
        const float* __restrict__ bias, void* __restrict__ outp) {
    int node = blockIdx.x * 4 + (threadIdx.x >> 6);
    int lane = threadIdx.x & 63;
    int e0 = row_ptr[node], e1 = row_ptr[node + 1];
    float acc[8] = {};
    for (int e = e0; e < e1; e++) {
        int s = col[e];
        float w = dinv[s];
        half8 v = *(const half8*)(hw + (size_t)s * ODIM + lane * 8);
#pragma unroll
        for (int j = 0; j < 8; j++) acc[j] = fmaf(w, (float)v[j], acc[j]);
    }
    float wd = dinv[node];
    float4 b0 = *(const float4*)(bias + lane * 8);
    float4 b1 = *(const float4*)(bias + lane * 8 + 4);
    float o[8];
    o[0] = fmaxf(fmaf(acc[0], wd, b0.x), 0.f);
    o[1] = fmaxf(fmaf(acc[1], wd, b0.y), 0.f);
    o[2] = fmaxf(fmaf(acc[2], wd, b0.z), 0.f);
    o[3] = fmaxf(fmaf(acc[3], wd, b0.w), 0.f);
    o[4] = fmaxf(fmaf(acc[4], wd, b1.x), 0.f);
    o[5] = fmaxf(fmaf(acc[5], wd, b1.y), 0.f);
    o[6] = fmaxf(fmaf(acc[6], wd, b1.z), 0.f);
    o[7] = fmaxf(fmaf(acc[7], wd, b1.w), 0.f);
    if (HALF_OUT) {
        half8 h;
#pragma unroll
        for (int j = 0; j < 8; j++) h[j] = (_Float16)o[j];
        *(half8*)((_Float16*)outp + (size_t)node * ODIM + lane * 8) = h;
    } else {
        float* out = (float*)outp;
        float4 f0 = {o[0], o[1], o[2], o[3]}, f1 = {o[4], o[5], o[6], o[7]};
        *(float4*)(out + (size_t)node * ODIM + lane * 8)     = f0;
        *(float4*)(out + (size_t)node * ODIM + lane * 8 + 4) = f1;
    }
}

extern "C" void kernel_launch(void* const* d_in, const int* in_sizes, int n_in,
                              void* d_out, int out_size, void* d_ws, size_t ws_size,
                              hipStream_t stream) {
    const float* x  = (const float*)d_in[0];
    const float* W1 = (const float*)d_in[1];
    const float* b1 = (const float*)d_in[2];
    const float* W2 = (const float*)d_in[3];
    const float* b2 = (const float*)d_in[4];
    float* out = (float*)d_out;
    char* ws = (char*)d_ws;

    _Float16* xhi  = (_Float16*)(ws + XHI_OFF);
    float* candv   = (float*)(ws + CANDV_OFF);
    unsigned short* candi = (unsigned short*)(ws + CANDI_OFF);
    float* sq      = (float*)(ws + SQ_OFF);
    int*   knn     = (int*)  (ws + KNN_OFF);
    float* dinv    = (float*)(ws + DINV_OFF);
    int*   row_ptr = (int*)  (ws + RPTR_OFF);
    int*   col     = (int*)  (ws + COL_OFF);
    _Float16* w1t  = (_Float16*)(ws + W1T_OFF);
    _Float16* w2t  = (_Float16*)(ws + W2T_OFF);
    _Float16* hw   = (_Float16*)(ws + HW_OFF);
    _Float16* h1h  = (_Float16*)(ws + H1H_OFF);

    prep_kernel<<<1888, 256, 0, stream>>>(x, xhi, sq, W1, w1t, W2, w2t);
    gram_hgemm_kernel<<<GRID_G + GRID_H1, 256, 0, stream>>>(xhi, sq, candv, candi, w1t, hw);
    knn_select_kernel<<<N_NODES / 4, 256, 0, stream>>>(candv, candi, x, sq, knn);
    graph_build_kernel<<<1, 1024, 0, stream>>>(knn, dinv, row_ptr, col);

    aggregate_kernel<true><<<N_NODES / 4, 256, 0, stream>>>(hw, row_ptr, col, dinv, b1, (void*)h1h);
    hgemm_nt_kernel<<<(N_NODES / 64) * (ODIM / 128), 256, 0, stream>>>(h1h, w2t, hw, N_NODES, ODIM, ODIM);
    aggregate_kernel<false><<<N_NODES / 4, 256, 0, stream>>>(hw, row_ptr, col, dinv, b2, (void*)out);
}